// Round 5
// baseline (882.041 us; speedup 1.0000x reference)
//
#include <hip/hip_runtime.h>

#define N_NODES 50000
#define N_EDGES 600000
#define N_GRAPHS 500
#define IN_F 92
#define HID 64
#define EDGE_F 41
#define ZDIM 169
#define PRED 128
#define BN_EPS 1e-5f
#define SCAN_BLOCKS 196          // ceil(50000/256)
#define ROW_U32 24               // eapS row = 48 f16 = 96 B

typedef unsigned int u32;
typedef _Float16 f16;
typedef _Float16 f16x2 __attribute__((ext_vector_type(2)));
typedef _Float16 f16x8 __attribute__((ext_vector_type(8)));
typedef float f32x4 __attribute__((ext_vector_type(4)));

// f32 -> bf16 round-to-nearest-even
__device__ __forceinline__ u32 f2bf(float f) {
    u32 u = __float_as_uint(f);
    return (u + 0x7fffu + ((u >> 16) & 1u)) >> 16;
}

__device__ __forceinline__ float edge_msg(float s_, float p_) {
    float g_ = __builtin_amdgcn_rcpf(1.f + __expf(-s_));
    float m_ = fmaxf(p_, 0.f) + __logf(1.f + __expf(-fabsf(p_)));
    return g_ * m_;
}

// first idx in [0, nelem) with a[idx] >= val (a sorted ascending)
__device__ __forceinline__ int lbound(const int* __restrict__ a, int nelem, int val) {
    int lo = 0, hi = nelem;
    while (lo < hi) {
        int m = (lo + hi) >> 1;
        if (a[m] < val) lo = m + 1; else hi = m;
    }
    return lo;
}

// ---------------- embed: A = x @ W_embed + b_embed ----------------
__global__ __launch_bounds__(256) void k_embed(const float* __restrict__ x,
                                               const float* __restrict__ W,
                                               const float* __restrict__ b,
                                               float* __restrict__ A) {
    __shared__ float Wl[IN_F * HID];
    for (int idx = threadIdx.x; idx < IN_F * HID; idx += 256) Wl[idx] = W[idx];
    __syncthreads();
    const int lane = threadIdx.x & 63;
    const int wid = blockIdx.x * 4 + (threadIdx.x >> 6);
    const int nwaves = gridDim.x * 4;
    const float bj = b[lane];
    for (int r0 = wid * 4; r0 < N_NODES; r0 += nwaves * 4) {
        const float* x0 = x + (size_t)r0 * IN_F;
        float a0 = bj, a1 = bj, a2 = bj, a3 = bj;
        #pragma unroll 4
        for (int k = 0; k < IN_F; ++k) {
            float w = Wl[k * HID + lane];
            a0 += x0[k] * w;
            a1 += x0[IN_F + k] * w;
            a2 += x0[2 * IN_F + k] * w;
            a3 += x0[3 * IN_F + k] * w;
        }
        A[(size_t)(r0 + 0) * HID + lane] = a0;
        A[(size_t)(r0 + 1) * HID + lane] = a1;
        A[(size_t)(r0 + 2) * HID + lane] = a2;
        A[(size_t)(r0 + 3) * HID + lane] = a3;
    }
}

// ---------------- CSR build ----------------
__global__ void k_zeroi(int* __restrict__ p, int n) {
    int i = blockIdx.x * 256 + threadIdx.x;
    if (i < n) p[i] = 0;
}

__global__ void k_hist(const int* __restrict__ dst, int* __restrict__ deg) {
    int e = blockIdx.x * 256 + threadIdx.x;
    if (e < N_EDGES) atomicAdd(&deg[dst[e]], 1);
}

__global__ __launch_bounds__(256) void k_scanA(const int* __restrict__ deg,
                                               int* __restrict__ partial) {
    __shared__ int s[256];
    int i = blockIdx.x * 256 + threadIdx.x;
    s[threadIdx.x] = (i < N_NODES) ? deg[i] : 0;
    __syncthreads();
    for (int off = 128; off > 0; off >>= 1) {
        if (threadIdx.x < off) s[threadIdx.x] += s[threadIdx.x + off];
        __syncthreads();
    }
    if (threadIdx.x == 0) partial[blockIdx.x] = s[0];
}

__global__ __launch_bounds__(256) void k_scanB(const int* __restrict__ partial,
                                               int* __restrict__ partialExc,
                                               int* __restrict__ rowptr) {
    __shared__ int s[256];
    int t = threadIdx.x;
    int v = (t < SCAN_BLOCKS) ? partial[t] : 0;
    s[t] = v;
    __syncthreads();
    for (int off = 1; off < 256; off <<= 1) {
        int x = (t >= off) ? s[t - off] : 0;
        __syncthreads();
        s[t] += x;
        __syncthreads();
    }
    partialExc[t] = s[t] - v;
    if (t == 0) rowptr[N_NODES] = N_EDGES;
}

__global__ __launch_bounds__(256) void k_scanC(const int* __restrict__ deg,
                                               const int* __restrict__ partialExc,
                                               int* __restrict__ rowptr) {
    __shared__ int s[256];
    int i = blockIdx.x * 256 + threadIdx.x;
    int t = threadIdx.x;
    int v = (i < N_NODES) ? deg[i] : 0;
    s[t] = v;
    __syncthreads();
    for (int off = 1; off < 256; off <<= 1) {
        int x = (t >= off) ? s[t - off] : 0;
        __syncthreads();
        s[t] += x;
        __syncthreads();
    }
    if (i < N_NODES) rowptr[i] = s[t] - v + partialExc[blockIdx.x];
}

// ---------------- rank: CSR slot assignment (perm only) ----------------
__global__ void k_rank(const int* __restrict__ dst, const int* __restrict__ src,
                       const int* __restrict__ rowptr, int* __restrict__ cursor,
                       int* __restrict__ srcS, int* __restrict__ iperm) {
    int e = blockIdx.x * 256 + threadIdx.x;
    if (e >= N_EDGES) return;
    int d = dst[e];
    int p = rowptr[d] + atomicAdd(&cursor[d], 1);
    srcS[p] = src[e];
    iperm[p] = e;
}

// ---------------- epackS: gather-permute ea rows -> f16, 96 B rows ----------
__global__ __launch_bounds__(256) void k_epackS(const float* __restrict__ ea,
                                                const int* __restrict__ iperm,
                                                u32* __restrict__ eapS) {
    const int total = N_EDGES * ROW_U32;
    const int stride = gridDim.x * 256;
    for (int idx = blockIdx.x * 256 + threadIdx.x; idx < total; idx += stride) {
        int p = idx / ROW_U32;
        int q = idx - p * ROW_U32;
        int e = iperm[p];
        int k0 = 2 * q, k1 = k0 + 1;
        float f0 = (k0 < EDGE_F) ? ea[(size_t)e * EDGE_F + k0] : 0.f;
        float f1 = (k1 < EDGE_F) ? ea[(size_t)e * EDGE_F + k1] : 0.f;
        f16x2 hv = {(f16)f0, (f16)f1};
        eapS[idx] = __builtin_bit_cast(u32, hv);
    }
}

// ---------------- wprep: edge-weight rows -> MFMA B-fragment order, f16 ------
// Wf16[L][kt][jt][lane][8]; B[k][j128]: k = kt*32+(lane>>4)*8+b (0 for k>=41),
// j128 = jt*16+(lane&15); j128<64 -> sig col, else sp col.
__global__ void k_wprep(const float* __restrict__ Wsig, const float* __restrict__ Wsp,
                        f16* __restrict__ Wf16) {
    int t = blockIdx.x * 256 + threadIdx.x;
    if (t >= 3 * 2 * 8 * 64) return;
    int lane = t & 63;
    int jt = (t >> 6) & 7;
    int kt = (t >> 9) & 1;
    int L = t >> 10;
    int j128 = jt * 16 + (lane & 15);
    const float* Wbase = (j128 < 64) ? Wsig : Wsp;
    int j = j128 & 63;
    f16x8 v;
    #pragma unroll
    for (int b = 0; b < 8; ++b) {
        int k = kt * 32 + (lane >> 4) * 8 + b;
        float f = (k < EDGE_F) ? Wbase[(size_t)L * ZDIM * HID + (128 + k) * HID + j] : 0.f;
        v[b] = (f16)f;
    }
    *(f16x8*)(Wf16 + ((size_t)((L * 2 + kt) * 8 + jt) * 64 + lane) * 8) = v;
}

// ---------------- wprep2: node-proj weights -> B-frags for k_projm ----------
// B is 64(k) x 256(j256): j256 0..63 = Wsig[k][j], 64..127 = Wsp[k][j],
// 128..191 = Wsig[64+k][j], 192..255 = Wsp[64+k][j].
__global__ void k_wprep2(const float* __restrict__ Wsig, const float* __restrict__ Wsp,
                         f16* __restrict__ Wp2) {
    int t = blockIdx.x * 256 + threadIdx.x;
    if (t >= 3 * 2 * 16 * 64) return;
    int lane = t & 63;
    int jt = (t >> 6) & 15;
    int kt = (t >> 10) & 1;
    int L = t >> 11;
    int j256 = jt * 16 + (lane & 15);
    const float* Wbase = (j256 & 64) ? Wsp : Wsig;
    int rowoff = (j256 & 128) ? 64 : 0;
    int j = j256 & 63;
    f16x8 v;
    #pragma unroll
    for (int b = 0; b < 8; ++b) {
        int k = kt * 32 + (lane >> 4) * 8 + b;   // always < 64
        v[b] = (f16)Wbase[(size_t)L * ZDIM * HID + (rowoff + k) * HID + j];
    }
    *(f16x8*)(Wp2 + ((size_t)((L * 2 + kt) * 16 + jt) * 64 + lane) * 8) = v;
}

// ---------------- projm: MFMA node projections (BN fused), zero statsOut ----
__global__ __launch_bounds__(256, 4) void k_projm(const float* __restrict__ A,
                                                  const float* __restrict__ statsPrev,
                                                  const float* __restrict__ gammaP,
                                                  const float* __restrict__ betaP,
                                                  int applyBN,
                                                  const f16* __restrict__ Wp2L,
                                                  const float* __restrict__ bsig,
                                                  const float* __restrict__ bsp,
                                                  u32* __restrict__ pA,
                                                  u32* __restrict__ pB,
                                                  float* __restrict__ statsOut) {
    __shared__ f16x8 Wl[32 * 64];   // 32 KB
    for (int i = threadIdx.x; i < 32 * 64; i += 256) Wl[i] = ((const f16x8*)Wp2L)[i];
    if (blockIdx.x == 0)
        for (int i = threadIdx.x; i < 128 * 32; i += 256) statsOut[i] = 0.f;
    __syncthreads();
    const int lane = threadIdx.x & 63;
    const int col = lane & 15;
    // per-lane BN scale/shift for its 16 k positions
    float sck[2][8], shk[2][8];
    #pragma unroll
    for (int kt = 0; kt < 2; ++kt)
        #pragma unroll
        for (int b = 0; b < 8; ++b) {
            int k = kt * 32 + (lane >> 4) * 8 + b;
            float scv = 1.f, shv = 0.f;
            if (applyBN) {
                float m = statsPrev[k * 32] * (1.f / N_NODES);
                float v = statsPrev[(64 + k) * 32] * (1.f / N_NODES) - m * m;
                scv = rsqrtf(v + BN_EPS) * gammaP[k];
                shv = betaP[k] - m * scv;
            }
            sck[kt][b] = scv;
            shk[kt][b] = shv;
        }
    float bA[4], bP[4];
    #pragma unroll
    for (int jt = 0; jt < 4; ++jt) {
        bA[jt] = bsig[jt * 16 + col];
        bP[jt] = bsp[jt * 16 + col];
    }
    const int wid = blockIdx.x * 4 + (threadIdx.x >> 6);
    const int nw = gridDim.x * 4;
    for (int c = wid; c < N_NODES / 16; c += nw) {
        const int node = c * 16 + col;
        const float4* Arow = (const float4*)(A + (size_t)node * HID);
        f16x8 af[2];
        #pragma unroll
        for (int kt = 0; kt < 2; ++kt) {
            float4 v0 = Arow[kt * 8 + (lane >> 4) * 2];
            float4 v1 = Arow[kt * 8 + (lane >> 4) * 2 + 1];
            float e0 = v0.x * sck[kt][0] + shk[kt][0];
            float e1 = v0.y * sck[kt][1] + shk[kt][1];
            float e2 = v0.z * sck[kt][2] + shk[kt][2];
            float e3 = v0.w * sck[kt][3] + shk[kt][3];
            float e4 = v1.x * sck[kt][4] + shk[kt][4];
            float e5 = v1.y * sck[kt][5] + shk[kt][5];
            float e6 = v1.z * sck[kt][6] + shk[kt][6];
            float e7 = v1.w * sck[kt][7] + shk[kt][7];
            af[kt] = f16x8{(f16)e0, (f16)e1, (f16)e2, (f16)e3,
                           (f16)e4, (f16)e5, (f16)e6, (f16)e7};
        }
        #pragma unroll
        for (int h = 0; h < 2; ++h) {
            f32x4 c4[8];
            #pragma unroll
            for (int jt2 = 0; jt2 < 8; ++jt2) {
                int jt = h * 8 + jt2;
                f32x4 acc = {};
                acc = __builtin_amdgcn_mfma_f32_16x16x32_f16(af[0], Wl[(0 * 16 + jt) * 64 + lane], acc, 0, 0, 0);
                c4[jt2] = __builtin_amdgcn_mfma_f32_16x16x32_f16(af[1], Wl[(1 * 16 + jt) * 64 + lane], acc, 0, 0, 0);
            }
            u32* dstArr = h ? pB : pA;
            #pragma unroll
            for (int jt2 = 0; jt2 < 4; ++jt2)
                #pragma unroll
                for (int r = 0; r < 4; ++r) {
                    float s = c4[jt2][r] + (h ? 0.f : bA[jt2]);
                    float p = c4[jt2 + 4][r] + (h ? 0.f : bP[jt2]);
                    int n2 = c * 16 + (lane >> 4) * 4 + r;
                    dstArr[(size_t)n2 * HID + jt2 * 16 + col] = f2bf(s) | (f2bf(p) << 16);
                }
        }
    }
}

// ---------------- nodeagg: edge-contiguous MFMA tiles, edge-balanced waves ---
__global__ __launch_bounds__(256, 3) void k_nodeagg(const float* __restrict__ A,
                                                    const float* __restrict__ statsPrev,
                                                    const float* __restrict__ gammaP,
                                                    const float* __restrict__ betaP,
                                                    int applyBN,
                                                    const u32* __restrict__ pAv,
                                                    const u32* __restrict__ pBv,
                                                    const u32* __restrict__ eapS,
                                                    const int* __restrict__ srcS,
                                                    const int* __restrict__ rowptr,
                                                    const f16* __restrict__ Wf16L,
                                                    float* __restrict__ Aout,
                                                    float* __restrict__ statsOut) {
    __shared__ float2 pairsAll[4][16 * 66];   // per-wave [16 edge][66-pad 64 j] {sig,sp}
    __shared__ float redS[256], redQ[256];
    const int lane = threadIdx.x & 63;
    float2* pairs = pairsAll[threadIdx.x >> 6];

    // preload B-fragments: 16 x f16x8 = 64 VGPRs
    const f16x8* WfL = (const f16x8*)Wf16L;
    f16x8 bfrag[2][8];
    #pragma unroll
    for (int kt = 0; kt < 2; ++kt)
        #pragma unroll
        for (int jt = 0; jt < 8; ++jt)
            bfrag[kt][jt] = WfL[(kt * 8 + jt) * 64 + lane];

    float scL = 1.f, shL = 0.f;
    if (applyBN) {
        float m = statsPrev[lane * 32] * (1.f / N_NODES);
        float v = statsPrev[(64 + lane) * 32] * (1.f / N_NODES) - m * m;
        scL = rsqrtf(v + BN_EPS) * gammaP[lane];
        shL = betaP[lane] - m * scL;
    }

    // edge-balanced wave partition: wave owns nodes whose first edge is in
    // [w*T, (w+1)*T); node spans never split across waves.
    const int nwaves = gridDim.x << 2;
    const int w = (blockIdx.x << 2) + (threadIdx.x >> 6);
    const int T = (N_EDGES + 1 + nwaves - 1) / nwaves;
    const int lo_e = w * T;
    const int hi_e = lo_e + T;
    int nb = min(lbound(rowptr, N_NODES + 1, lo_e), N_NODES);
    int ne = min(lbound(rowptr, N_NODES + 1, hi_e), N_NODES);

    float lsum = 0.f, lsq = 0.f;
    int n = nb;
    float acc = 0.f, resid = 0.f, bsig = 0.f, bsp = 0.f;
    int re = 0;
    if (n < ne) {
        resid = A[(size_t)n * HID + lane];
        if (applyBN) resid = resid * scL + shL;
        u32 pb = pBv[(size_t)n * HID + lane];
        bsig = __uint_as_float(pb << 16);
        bsp = __uint_as_float(pb & 0xffff0000u);
        re = rowptr[n + 1];
        const int eb = rowptr[nb];
        const int eEnd = rowptr[ne];
        const int col = lane & 15, rowb = (lane >> 4) * 4;
        for (int tb = eb; tb < eEnd; tb += 16) {
            // gathers (issue early; guarded tail)
            u32 g[16];
            #pragma unroll
            for (int i2 = 0; i2 < 16; ++i2) {
                int ei = tb + i2;
                g[i2] = (ei < eEnd) ? pAv[(size_t)srcS[ei] * HID + lane] : 0u;
            }
            // phase A: MFMA dots for 16 contiguous edges
            const f16x8* arow = (const f16x8*)(eapS + (size_t)(tb + col) * ROW_U32);
            f16x8 a0 = arow[lane >> 4];        // k 0..31
            f16x8 a1 = arow[4 + (lane >> 4)];  // k 32..47 (+16 zero-weight k)
            f32x4 cc[8];
            #pragma unroll
            for (int jt = 0; jt < 8; ++jt) {
                f32x4 c = {};
                c = __builtin_amdgcn_mfma_f32_16x16x32_f16(a0, bfrag[0][jt], c, 0, 0, 0);
                cc[jt] = __builtin_amdgcn_mfma_f32_16x16x32_f16(a1, bfrag[1][jt], c, 0, 0, 0);
            }
            #pragma unroll
            for (int jt = 0; jt < 4; ++jt)
                #pragma unroll
                for (int r = 0; r < 4; ++r)
                    pairs[(rowb + r) * 66 + jt * 16 + col] = make_float2(cc[jt][r], cc[jt + 4][r]);
            // phase B: consume edges, flushing nodes at boundaries
            const int lim = min(16, eEnd - tb);
            for (int i2 = 0; i2 < lim; ++i2) {
                int e = tb + i2;
                while (e >= re) {   // node n complete (also drains deg-0 runs)
                    float outv = resid + acc;
                    Aout[(size_t)n * HID + lane] = outv;
                    lsum += outv;
                    lsq += outv * outv;
                    ++n;
                    resid = A[(size_t)n * HID + lane];
                    if (applyBN) resid = resid * scL + shL;
                    u32 pb2 = pBv[(size_t)n * HID + lane];
                    bsig = __uint_as_float(pb2 << 16);
                    bsp = __uint_as_float(pb2 & 0xffff0000u);
                    re = rowptr[n + 1];
                    acc = 0.f;
                }
                float2 d2 = pairs[i2 * 66 + lane];
                float s_ = d2.x + __uint_as_float(g[i2] << 16) + bsig;
                float p_ = d2.y + __uint_as_float(g[i2] & 0xffff0000u) + bsp;
                acc += edge_msg(s_, p_);
            }
        }
    }
    // drain remaining owned nodes (incl. trailing deg-0)
    while (n < ne) {
        float outv = resid + acc;
        Aout[(size_t)n * HID + lane] = outv;
        lsum += outv;
        lsq += outv * outv;
        ++n;
        acc = 0.f;
        if (n < ne) {
            resid = A[(size_t)n * HID + lane];
            if (applyBN) resid = resid * scL + shL;
        }
    }

    redS[threadIdx.x] = lsum;
    redQ[threadIdx.x] = lsq;
    __syncthreads();
    if (threadIdx.x < 64) {
        float s = redS[threadIdx.x] + redS[threadIdx.x + 64] + redS[threadIdx.x + 128] + redS[threadIdx.x + 192];
        float q = redQ[threadIdx.x] + redQ[threadIdx.x + 64] + redQ[threadIdx.x + 128] + redQ[threadIdx.x + 192];
        unsafeAtomicAdd(&statsOut[threadIdx.x * 32], s);
        unsafeAtomicAdd(&statsOut[(64 + threadIdx.x) * 32], q);
    }
}

__global__ void k_zerof(float* __restrict__ p, int n) {
    int i = blockIdx.x * blockDim.x + threadIdx.x;
    if (i < n) p[i] = 0.f;
}

// ---------------- pool (+ final BN): segment-sum over sorted graph_idx ------
__global__ __launch_bounds__(256) void k_poolbn(const float* __restrict__ A,
                                                const float* __restrict__ stats,
                                                const float* __restrict__ gamma,
                                                const float* __restrict__ beta,
                                                const int* __restrict__ gidx,
                                                float* __restrict__ gf) {
    const int lane = threadIdx.x & 63;
    float m = stats[lane * 32] * (1.f / N_NODES);
    float v = stats[(64 + lane) * 32] * (1.f / N_NODES) - m * m;
    float scv = rsqrtf(v + BN_EPS) * gamma[lane];
    float shv = beta[lane] - m * scv;
    const int wid = blockIdx.x * 4 + (threadIdx.x >> 6);
    const int nwaves = gridDim.x * 4;
    const int chunk = (N_NODES + nwaves - 1) / nwaves;
    int r0 = wid * chunk;
    if (r0 >= N_NODES) return;
    int r1 = min(r0 + chunk, N_NODES);
    int gcur = gidx[r0];
    float acc = 0.f;
    for (int r = r0; r < r1; ++r) {
        int g = gidx[r];
        if (g != gcur) {
            unsafeAtomicAdd(&gf[(size_t)gcur * HID + lane], acc);
            acc = 0.f;
            gcur = g;
        }
        acc += A[(size_t)r * HID + lane] * scv + shv;
    }
    unsafeAtomicAdd(&gf[(size_t)gcur * HID + lane], acc);
}

// ---------------- readout ----------------
__global__ __launch_bounds__(256) void k_readout(const float* __restrict__ gf,
                                                 const float* __restrict__ Wfc,
                                                 const float* __restrict__ bfc,
                                                 const float* __restrict__ Wout,
                                                 const float* __restrict__ bout,
                                                 float* __restrict__ out) {
    const int lane = threadIdx.x & 63;
    const int g = blockIdx.x * 4 + (threadIdx.x >> 6);
    if (g >= N_GRAPHS) return;
    const float* row = gf + (size_t)g * HID;
    float p0 = bfc[lane], p1 = bfc[64 + lane];
    #pragma unroll 4
    for (int k = 0; k < HID; ++k) {
        float v = row[k];
        p0 += v * Wfc[k * PRED + lane];
        p1 += v * Wfc[k * PRED + 64 + lane];
    }
    float part = p0 * Wout[lane] + p1 * Wout[64 + lane];
    #pragma unroll
    for (int off = 32; off > 0; off >>= 1) part += __shfl_xor(part, off);
    if (lane == 0) out[g] = part + bout[0];
}

extern "C" void kernel_launch(void* const* d_in, const int* in_sizes, int n_in,
                              void* d_out, int out_size, void* d_ws, size_t ws_size,
                              hipStream_t stream) {
    const float* x         = (const float*)d_in[0];
    const float* edge_attr = (const float*)d_in[1];
    const int*   src       = (const int*)d_in[2];
    const int*   dst       = (const int*)d_in[3];
    const int*   gidx      = (const int*)d_in[4];
    const float* W_embed   = (const float*)d_in[6];
    const float* b_embed   = (const float*)d_in[7];
    const float* W_sig     = (const float*)d_in[8];
    const float* b_sig     = (const float*)d_in[9];
    const float* W_sp      = (const float*)d_in[10];
    const float* b_sp      = (const float*)d_in[11];
    const float* bn_gamma  = (const float*)d_in[12];
    const float* bn_beta   = (const float*)d_in[13];
    const float* W_fc      = (const float*)d_in[14];
    const float* b_fc      = (const float*)d_in[15];
    const float* W_out     = (const float*)d_in[16];
    const float* b_out     = (const float*)d_in[17];
    float* out = (float*)d_out;

    const size_t NH = (size_t)N_NODES * HID;
    float* ws     = (float*)d_ws;
    float* A      = ws;                                   // NH f32
    u32*   pA     = (u32*)(A + NH);                       // NH u32 (bf16x2)
    u32*   pB     = pA + NH;                              // NH u32
    u32*   eapS   = pB + NH;                              // (E+18)*24 u32 (f16, dst-sorted, 96B rows)
    int*   srcS   = (int*)(eapS + (size_t)(N_EDGES + 18) * ROW_U32);  // E
    int*   iperm  = srcS + N_EDGES;                       // E
    int*   rowptr = iperm + N_EDGES;                      // N+1
    int*   deg    = rowptr + N_NODES + 1;                 // N
    int*   cursor = deg + N_NODES;                        // N
    int*   partial    = cursor + N_NODES;                 // 256
    int*   partialExc = partial + 256;                    // 256
    f16*   Wf16   = (f16*)(partialExc + 256);             // 3*2*8*64*8 f16 = 48 KB
    f16*   Wp2    = Wf16 + 3 * 2 * 8 * 64 * 8;            // 3*2*16*64*8 f16 = 96 KB
    float* stats  = (float*)(Wp2 + 3 * 2 * 16 * 64 * 8);  // 3 * 4096 f32
    float* gf     = stats + 3 * 4096;                     // G*HID

    k_embed<<<512, 256, 0, stream>>>(x, W_embed, b_embed, A);

    // ---- CSR build + packs (once per call) ----
    k_zeroi<<<(2 * N_NODES + 255) / 256, 256, 0, stream>>>(deg, 2 * N_NODES);  // deg+cursor
    k_hist<<<(N_EDGES + 255) / 256, 256, 0, stream>>>(dst, deg);
    k_scanA<<<SCAN_BLOCKS, 256, 0, stream>>>(deg, partial);
    k_scanB<<<1, 256, 0, stream>>>(partial, partialExc, rowptr);
    k_scanC<<<SCAN_BLOCKS, 256, 0, stream>>>(deg, partialExc, rowptr);
    k_wprep<<<12, 256, 0, stream>>>(W_sig, W_sp, Wf16);
    k_wprep2<<<24, 256, 0, stream>>>(W_sig, W_sp, Wp2);
    k_rank<<<(N_EDGES + 255) / 256, 256, 0, stream>>>(dst, src, rowptr, cursor, srcS, iperm);
    k_epackS<<<4096, 256, 0, stream>>>(edge_attr, iperm, eapS);

    for (int i = 0; i < 3; ++i) {
        const float* stPrev = stats + (size_t)(i > 0 ? i - 1 : 0) * 4096;
        const float* gP     = bn_gamma + (i > 0 ? i - 1 : 0) * HID;
        const float* bP     = bn_beta + (i > 0 ? i - 1 : 0) * HID;
        float* stOut        = stats + (size_t)i * 4096;
        int applyBN = (i > 0) ? 1 : 0;
        k_projm<<<512, 256, 0, stream>>>(A, stPrev, gP, bP, applyBN,
                                         Wp2 + (size_t)i * 2 * 16 * 64 * 8,
                                         b_sig + i * HID, b_sp + i * HID,
                                         pA, pB, stOut);
        k_nodeagg<<<1024, 256, 0, stream>>>(A, stPrev, gP, bP, applyBN,
                                            pA, pB, eapS, srcS, rowptr,
                                            Wf16 + (size_t)i * 2 * 8 * 64 * 8,
                                            A, stOut);
    }

    k_zerof<<<(N_GRAPHS * HID + 255) / 256, 256, 0, stream>>>(gf, N_GRAPHS * HID);
    k_poolbn<<<256, 256, 0, stream>>>(A, stats + 2 * 4096, bn_gamma + 2 * HID,
                                      bn_beta + 2 * HID, gidx, gf);
    k_readout<<<(N_GRAPHS + 3) / 4, 256, 0, stream>>>(gf, W_fc, b_fc, W_out, b_out, out);
}

// Round 6
// 647.620 us; speedup vs baseline: 1.3620x; 1.3620x over previous
//
#include <hip/hip_runtime.h>

#define N_NODES 50000
#define N_EDGES 600000
#define N_GRAPHS 500
#define IN_F 92
#define HID 64
#define EDGE_F 41
#define ZDIM 169
#define PRED 128
#define BN_EPS 1e-5f
#define SCAN_BLOCKS 196          // ceil(50000/256)
#define ROW_U32 24               // eapS row = 48 f16 = 96 B

typedef unsigned int u32;
typedef _Float16 f16;
typedef _Float16 f16x2 __attribute__((ext_vector_type(2)));
typedef _Float16 f16x8 __attribute__((ext_vector_type(8)));
typedef float f32x4 __attribute__((ext_vector_type(4)));

// f32 -> bf16 round-to-nearest-even
__device__ __forceinline__ u32 f2bf(float f) {
    u32 u = __float_as_uint(f);
    return (u + 0x7fffu + ((u >> 16) & 1u)) >> 16;
}

__device__ __forceinline__ float edge_msg(float s_, float p_) {
    float g_ = __builtin_amdgcn_rcpf(1.f + __expf(-s_));
    float m_ = fmaxf(p_, 0.f) + __logf(1.f + __expf(-fabsf(p_)));
    return g_ * m_;
}

// first idx in [0, nelem) with a[idx] >= val (a sorted ascending)
__device__ __forceinline__ int lbound(const int* __restrict__ a, int nelem, int val) {
    int lo = 0, hi = nelem;
    while (lo < hi) {
        int m = (lo + hi) >> 1;
        if (a[m] < val) lo = m + 1; else hi = m;
    }
    return lo;
}

// ---------------- embed: A = x @ W_embed + b_embed ----------------
__global__ __launch_bounds__(256) void k_embed(const float* __restrict__ x,
                                               const float* __restrict__ W,
                                               const float* __restrict__ b,
                                               float* __restrict__ A) {
    __shared__ float Wl[IN_F * HID];
    for (int idx = threadIdx.x; idx < IN_F * HID; idx += 256) Wl[idx] = W[idx];
    __syncthreads();
    const int lane = threadIdx.x & 63;
    const int wid = blockIdx.x * 4 + (threadIdx.x >> 6);
    const int nwaves = gridDim.x * 4;
    const float bj = b[lane];
    for (int r0 = wid * 4; r0 < N_NODES; r0 += nwaves * 4) {
        const float* x0 = x + (size_t)r0 * IN_F;
        float a0 = bj, a1 = bj, a2 = bj, a3 = bj;
        #pragma unroll 4
        for (int k = 0; k < IN_F; ++k) {
            float w = Wl[k * HID + lane];
            a0 += x0[k] * w;
            a1 += x0[IN_F + k] * w;
            a2 += x0[2 * IN_F + k] * w;
            a3 += x0[3 * IN_F + k] * w;
        }
        A[(size_t)(r0 + 0) * HID + lane] = a0;
        A[(size_t)(r0 + 1) * HID + lane] = a1;
        A[(size_t)(r0 + 2) * HID + lane] = a2;
        A[(size_t)(r0 + 3) * HID + lane] = a3;
    }
}

// ---------------- CSR build ----------------
__global__ void k_zeroi(int* __restrict__ p, int n) {
    int i = blockIdx.x * 256 + threadIdx.x;
    if (i < n) p[i] = 0;
}

__global__ void k_hist(const int* __restrict__ dst, int* __restrict__ deg) {
    int e = blockIdx.x * 256 + threadIdx.x;
    if (e < N_EDGES) atomicAdd(&deg[dst[e]], 1);
}

__global__ __launch_bounds__(256) void k_scanA(const int* __restrict__ deg,
                                               int* __restrict__ partial) {
    __shared__ int s[256];
    int i = blockIdx.x * 256 + threadIdx.x;
    s[threadIdx.x] = (i < N_NODES) ? deg[i] : 0;
    __syncthreads();
    for (int off = 128; off > 0; off >>= 1) {
        if (threadIdx.x < off) s[threadIdx.x] += s[threadIdx.x + off];
        __syncthreads();
    }
    if (threadIdx.x == 0) partial[blockIdx.x] = s[0];
}

__global__ __launch_bounds__(256) void k_scanB(const int* __restrict__ partial,
                                               int* __restrict__ partialExc,
                                               int* __restrict__ rowptr) {
    __shared__ int s[256];
    int t = threadIdx.x;
    int v = (t < SCAN_BLOCKS) ? partial[t] : 0;
    s[t] = v;
    __syncthreads();
    for (int off = 1; off < 256; off <<= 1) {
        int x = (t >= off) ? s[t - off] : 0;
        __syncthreads();
        s[t] += x;
        __syncthreads();
    }
    partialExc[t] = s[t] - v;
    if (t == 0) rowptr[N_NODES] = N_EDGES;
}

__global__ __launch_bounds__(256) void k_scanC(const int* __restrict__ deg,
                                               const int* __restrict__ partialExc,
                                               int* __restrict__ rowptr) {
    __shared__ int s[256];
    int i = blockIdx.x * 256 + threadIdx.x;
    int t = threadIdx.x;
    int v = (i < N_NODES) ? deg[i] : 0;
    s[t] = v;
    __syncthreads();
    for (int off = 1; off < 256; off <<= 1) {
        int x = (t >= off) ? s[t - off] : 0;
        __syncthreads();
        s[t] += x;
        __syncthreads();
    }
    if (i < N_NODES) rowptr[i] = s[t] - v + partialExc[blockIdx.x];
}

// ---------------- rank: CSR slot assignment (perm only); pads srcS tail ------
__global__ void k_rank(const int* __restrict__ dst, const int* __restrict__ src,
                       const int* __restrict__ rowptr, int* __restrict__ cursor,
                       int* __restrict__ srcS, int* __restrict__ iperm) {
    int e = blockIdx.x * 256 + threadIdx.x;
    if (e >= N_EDGES) {
        if (e < N_EDGES + 16) srcS[e] = 0;   // pad: tail int loads stay in-bounds
        return;
    }
    int d = dst[e];
    int p = rowptr[d] + atomicAdd(&cursor[d], 1);
    srcS[p] = src[e];
    iperm[p] = e;
}

// ---------------- epackS: gather-permute ea rows -> f16, 96 B rows ----------
__global__ __launch_bounds__(256) void k_epackS(const float* __restrict__ ea,
                                                const int* __restrict__ iperm,
                                                u32* __restrict__ eapS) {
    const int total = N_EDGES * ROW_U32;
    const int stride = gridDim.x * 256;
    for (int idx = blockIdx.x * 256 + threadIdx.x; idx < total; idx += stride) {
        int p = idx / ROW_U32;
        int q = idx - p * ROW_U32;
        int e = iperm[p];
        int k0 = 2 * q, k1 = k0 + 1;
        float f0 = (k0 < EDGE_F) ? ea[(size_t)e * EDGE_F + k0] : 0.f;
        float f1 = (k1 < EDGE_F) ? ea[(size_t)e * EDGE_F + k1] : 0.f;
        f16x2 hv = {(f16)f0, (f16)f1};
        eapS[idx] = __builtin_bit_cast(u32, hv);
    }
}

// ---------------- wprep: edge-weight rows -> MFMA B-fragment order, f16 ------
__global__ void k_wprep(const float* __restrict__ Wsig, const float* __restrict__ Wsp,
                        f16* __restrict__ Wf16) {
    int t = blockIdx.x * 256 + threadIdx.x;
    if (t >= 3 * 2 * 8 * 64) return;
    int lane = t & 63;
    int jt = (t >> 6) & 7;
    int kt = (t >> 9) & 1;
    int L = t >> 10;
    int j128 = jt * 16 + (lane & 15);
    const float* Wbase = (j128 < 64) ? Wsig : Wsp;
    int j = j128 & 63;
    f16x8 v;
    #pragma unroll
    for (int b = 0; b < 8; ++b) {
        int k = kt * 32 + (lane >> 4) * 8 + b;
        float f = (k < EDGE_F) ? Wbase[(size_t)L * ZDIM * HID + (128 + k) * HID + j] : 0.f;
        v[b] = (f16)f;
    }
    *(f16x8*)(Wf16 + ((size_t)((L * 2 + kt) * 8 + jt) * 64 + lane) * 8) = v;
}

// ---------------- wprep2: node-proj weights -> B-frags for k_projm ----------
__global__ void k_wprep2(const float* __restrict__ Wsig, const float* __restrict__ Wsp,
                         f16* __restrict__ Wp2) {
    int t = blockIdx.x * 256 + threadIdx.x;
    if (t >= 3 * 2 * 16 * 64) return;
    int lane = t & 63;
    int jt = (t >> 6) & 15;
    int kt = (t >> 10) & 1;
    int L = t >> 11;
    int j256 = jt * 16 + (lane & 15);
    const float* Wbase = (j256 & 64) ? Wsp : Wsig;
    int rowoff = (j256 & 128) ? 64 : 0;
    int j = j256 & 63;
    f16x8 v;
    #pragma unroll
    for (int b = 0; b < 8; ++b) {
        int k = kt * 32 + (lane >> 4) * 8 + b;   // always < 64
        v[b] = (f16)Wbase[(size_t)L * ZDIM * HID + (rowoff + k) * HID + j];
    }
    *(f16x8*)(Wp2 + ((size_t)((L * 2 + kt) * 16 + jt) * 64 + lane) * 8) = v;
}

// ---------------- projm: MFMA node projections (BN fused), zero statsOut ----
__global__ __launch_bounds__(256, 4) void k_projm(const float* __restrict__ A,
                                                  const float* __restrict__ statsPrev,
                                                  const float* __restrict__ gammaP,
                                                  const float* __restrict__ betaP,
                                                  int applyBN,
                                                  const f16* __restrict__ Wp2L,
                                                  const float* __restrict__ bsig,
                                                  const float* __restrict__ bsp,
                                                  u32* __restrict__ pA,
                                                  u32* __restrict__ pB,
                                                  float* __restrict__ statsOut) {
    __shared__ f16x8 Wl[32 * 64];   // 32 KB
    for (int i = threadIdx.x; i < 32 * 64; i += 256) Wl[i] = ((const f16x8*)Wp2L)[i];
    if (blockIdx.x == 0)
        for (int i = threadIdx.x; i < 128 * 32; i += 256) statsOut[i] = 0.f;
    __syncthreads();
    const int lane = threadIdx.x & 63;
    const int col = lane & 15;
    float sck[2][8], shk[2][8];
    #pragma unroll
    for (int kt = 0; kt < 2; ++kt)
        #pragma unroll
        for (int b = 0; b < 8; ++b) {
            int k = kt * 32 + (lane >> 4) * 8 + b;
            float scv = 1.f, shv = 0.f;
            if (applyBN) {
                float m = statsPrev[k * 32] * (1.f / N_NODES);
                float v = statsPrev[(64 + k) * 32] * (1.f / N_NODES) - m * m;
                scv = rsqrtf(v + BN_EPS) * gammaP[k];
                shv = betaP[k] - m * scv;
            }
            sck[kt][b] = scv;
            shk[kt][b] = shv;
        }
    float bA[4], bP[4];
    #pragma unroll
    for (int jt = 0; jt < 4; ++jt) {
        bA[jt] = bsig[jt * 16 + col];
        bP[jt] = bsp[jt * 16 + col];
    }
    const int wid = blockIdx.x * 4 + (threadIdx.x >> 6);
    const int nw = gridDim.x * 4;
    for (int c = wid; c < N_NODES / 16; c += nw) {
        const int node = c * 16 + col;
        const float4* Arow = (const float4*)(A + (size_t)node * HID);
        f16x8 af[2];
        #pragma unroll
        for (int kt = 0; kt < 2; ++kt) {
            float4 v0 = Arow[kt * 8 + (lane >> 4) * 2];
            float4 v1 = Arow[kt * 8 + (lane >> 4) * 2 + 1];
            float e0 = v0.x * sck[kt][0] + shk[kt][0];
            float e1 = v0.y * sck[kt][1] + shk[kt][1];
            float e2 = v0.z * sck[kt][2] + shk[kt][2];
            float e3 = v0.w * sck[kt][3] + shk[kt][3];
            float e4 = v1.x * sck[kt][4] + shk[kt][4];
            float e5 = v1.y * sck[kt][5] + shk[kt][5];
            float e6 = v1.z * sck[kt][6] + shk[kt][6];
            float e7 = v1.w * sck[kt][7] + shk[kt][7];
            af[kt] = f16x8{(f16)e0, (f16)e1, (f16)e2, (f16)e3,
                           (f16)e4, (f16)e5, (f16)e6, (f16)e7};
        }
        #pragma unroll
        for (int h = 0; h < 2; ++h) {
            f32x4 c4[8];
            #pragma unroll
            for (int jt2 = 0; jt2 < 8; ++jt2) {
                int jt = h * 8 + jt2;
                f32x4 acc = {};
                acc = __builtin_amdgcn_mfma_f32_16x16x32_f16(af[0], Wl[(0 * 16 + jt) * 64 + lane], acc, 0, 0, 0);
                c4[jt2] = __builtin_amdgcn_mfma_f32_16x16x32_f16(af[1], Wl[(1 * 16 + jt) * 64 + lane], acc, 0, 0, 0);
            }
            u32* dstArr = h ? pB : pA;
            #pragma unroll
            for (int jt2 = 0; jt2 < 4; ++jt2)
                #pragma unroll
                for (int r = 0; r < 4; ++r) {
                    float s = c4[jt2][r] + (h ? 0.f : bA[jt2]);
                    float p = c4[jt2 + 4][r] + (h ? 0.f : bP[jt2]);
                    int n2 = c * 16 + (lane >> 4) * 4 + r;
                    dstArr[(size_t)n2 * HID + jt2 * 16 + col] = f2bf(s) | (f2bf(p) << 16);
                }
        }
    }
}

// ---------------- nodeagg: node-aligned MFMA tiles, LDS-free epilogue -------
// Per node, per 16-edge tile: MFMA dots consumed IN C-fragment layout
// (edge=(lane>>4)*4+r, j=jt*16+(lane&15)); gathers in same layout; masked
// accumulate into accv[jt]; per node 2 shfl_xor reduce + lane-select store.
__global__ __launch_bounds__(256) void k_nodeagg(const float* __restrict__ A,
                                                 const float* __restrict__ statsPrev,
                                                 const float* __restrict__ gammaP,
                                                 const float* __restrict__ betaP,
                                                 int applyBN,
                                                 const u32* __restrict__ pAv,
                                                 const u32* __restrict__ pBv,
                                                 const u32* __restrict__ eapS,
                                                 const int* __restrict__ srcS,
                                                 const int* __restrict__ rowptr,
                                                 const f16* __restrict__ Wf16L,
                                                 float* __restrict__ Aout,
                                                 float* __restrict__ statsOut) {
    const int lane = threadIdx.x & 63;
    const int col = lane & 15;
    const int grp = lane >> 4;
    const int rowb = grp * 4;

    // preload B-fragments: 16 x f16x8
    const f16x8* WfL = (const f16x8*)Wf16L;
    f16x8 bfrag[2][8];
    #pragma unroll
    for (int kt = 0; kt < 2; ++kt)
        #pragma unroll
        for (int jt = 0; jt < 8; ++jt)
            bfrag[kt][jt] = WfL[(kt * 8 + jt) * 64 + lane];

    float scL = 1.f, shL = 0.f;
    if (applyBN) {
        float m = statsPrev[lane * 32] * (1.f / N_NODES);
        float v = statsPrev[(64 + lane) * 32] * (1.f / N_NODES) - m * m;
        scL = rsqrtf(v + BN_EPS) * gammaP[lane];
        shL = betaP[lane] - m * scL;
    }

    // edge-balanced wave partition (node spans never split)
    const int nwaves = gridDim.x << 2;
    const int w = (blockIdx.x << 2) + (threadIdx.x >> 6);
    const int T = (N_EDGES + 1 + nwaves - 1) / nwaves;
    int nb = min(lbound(rowptr, N_NODES + 1, w * T), N_NODES);
    int ne = min(lbound(rowptr, N_NODES + 1, w * T + T), N_NODES);

    float lsum = 0.f, lsq = 0.f;
    for (int n = nb; n < ne; ++n) {
        const int rb = rowptr[n], re = rowptr[n + 1];
        float resid = A[(size_t)n * HID + lane];
        if (applyBN) resid = resid * scL + shL;
        float bsigj[4], bspj[4];
        #pragma unroll
        for (int jt = 0; jt < 4; ++jt) {
            u32 pb = pBv[(size_t)n * HID + jt * 16 + col];
            bsigj[jt] = __uint_as_float(pb << 16);
            bspj[jt] = __uint_as_float(pb & 0xffff0000u);
        }
        float accv[4] = {0.f, 0.f, 0.f, 0.f};
        for (int et = rb; et < re; et += 16) {
            const int cnt = re - et;   // >16 means full tile
            // src indices for this lane's 4 edge rows (reads ≤15 past re: padded)
            int s0 = srcS[et + rowb + 0];
            int s1 = srcS[et + rowb + 1];
            int s2 = srcS[et + rowb + 2];
            int s3 = srcS[et + rowb + 3];
            // all 16 gathers up-front (latency overlap with MFMA)
            u32 ga[4][4];
            #pragma unroll
            for (int jt = 0; jt < 4; ++jt) {
                ga[jt][0] = pAv[(size_t)s0 * HID + jt * 16 + col];
                ga[jt][1] = pAv[(size_t)s1 * HID + jt * 16 + col];
                ga[jt][2] = pAv[(size_t)s2 * HID + jt * 16 + col];
                ga[jt][3] = pAv[(size_t)s3 * HID + jt * 16 + col];
            }
            // A-fragments (16 contiguous edge rows; pad rows masked below)
            const f16x8* arow = (const f16x8*)(eapS + (size_t)(et + col) * ROW_U32);
            f16x8 a0 = arow[grp];
            f16x8 a1 = arow[4 + grp];
            #pragma unroll
            for (int jt = 0; jt < 4; ++jt) {
                f32x4 cs = {}, cp = {};
                cs = __builtin_amdgcn_mfma_f32_16x16x32_f16(a0, bfrag[0][jt], cs, 0, 0, 0);
                cs = __builtin_amdgcn_mfma_f32_16x16x32_f16(a1, bfrag[1][jt], cs, 0, 0, 0);
                cp = __builtin_amdgcn_mfma_f32_16x16x32_f16(a0, bfrag[0][jt + 4], cp, 0, 0, 0);
                cp = __builtin_amdgcn_mfma_f32_16x16x32_f16(a1, bfrag[1][jt + 4], cp, 0, 0, 0);
                #pragma unroll
                for (int r = 0; r < 4; ++r) {
                    float s_ = cs[r] + __uint_as_float(ga[jt][r] << 16) + bsigj[jt];
                    float p_ = cp[r] + __uint_as_float(ga[jt][r] & 0xffff0000u) + bspj[jt];
                    float msg = edge_msg(s_, p_);
                    accv[jt] += (rowb + r < cnt) ? msg : 0.f;
                }
            }
        }
        // reduce the 4 row-groups; every lane then holds full sums for its col
        #pragma unroll
        for (int jt = 0; jt < 4; ++jt) {
            accv[jt] += __shfl_xor(accv[jt], 16);
            accv[jt] += __shfl_xor(accv[jt], 32);
        }
        float accSel = (lane & 32) ? ((lane & 16) ? accv[3] : accv[2])
                                   : ((lane & 16) ? accv[1] : accv[0]);
        float outv = resid + accSel;   // feature j = (grp*16+col) == lane
        Aout[(size_t)n * HID + lane] = outv;
        lsum += outv;
        lsq += outv * outv;
    }

    __shared__ float redS[256], redQ[256];
    redS[threadIdx.x] = lsum;
    redQ[threadIdx.x] = lsq;
    __syncthreads();
    if (threadIdx.x < 64) {
        float s = redS[threadIdx.x] + redS[threadIdx.x + 64] + redS[threadIdx.x + 128] + redS[threadIdx.x + 192];
        float q = redQ[threadIdx.x] + redQ[threadIdx.x + 64] + redQ[threadIdx.x + 128] + redQ[threadIdx.x + 192];
        unsafeAtomicAdd(&statsOut[threadIdx.x * 32], s);
        unsafeAtomicAdd(&statsOut[(64 + threadIdx.x) * 32], q);
    }
}

__global__ void k_zerof(float* __restrict__ p, int n) {
    int i = blockIdx.x * blockDim.x + threadIdx.x;
    if (i < n) p[i] = 0.f;
}

// ---------------- pool (+ final BN): segment-sum over sorted graph_idx ------
__global__ __launch_bounds__(256) void k_poolbn(const float* __restrict__ A,
                                                const float* __restrict__ stats,
                                                const float* __restrict__ gamma,
                                                const float* __restrict__ beta,
                                                const int* __restrict__ gidx,
                                                float* __restrict__ gf) {
    const int lane = threadIdx.x & 63;
    float m = stats[lane * 32] * (1.f / N_NODES);
    float v = stats[(64 + lane) * 32] * (1.f / N_NODES) - m * m;
    float scv = rsqrtf(v + BN_EPS) * gamma[lane];
    float shv = beta[lane] - m * scv;
    const int wid = blockIdx.x * 4 + (threadIdx.x >> 6);
    const int nwaves = gridDim.x * 4;
    const int chunk = (N_NODES + nwaves - 1) / nwaves;
    int r0 = wid * chunk;
    if (r0 >= N_NODES) return;
    int r1 = min(r0 + chunk, N_NODES);
    int gcur = gidx[r0];
    float acc = 0.f;
    for (int r = r0; r < r1; ++r) {
        int g = gidx[r];
        if (g != gcur) {
            unsafeAtomicAdd(&gf[(size_t)gcur * HID + lane], acc);
            acc = 0.f;
            gcur = g;
        }
        acc += A[(size_t)r * HID + lane] * scv + shv;
    }
    unsafeAtomicAdd(&gf[(size_t)gcur * HID + lane], acc);
}

// ---------------- readout ----------------
__global__ __launch_bounds__(256) void k_readout(const float* __restrict__ gf,
                                                 const float* __restrict__ Wfc,
                                                 const float* __restrict__ bfc,
                                                 const float* __restrict__ Wout,
                                                 const float* __restrict__ bout,
                                                 float* __restrict__ out) {
    const int lane = threadIdx.x & 63;
    const int g = blockIdx.x * 4 + (threadIdx.x >> 6);
    if (g >= N_GRAPHS) return;
    const float* row = gf + (size_t)g * HID;
    float p0 = bfc[lane], p1 = bfc[64 + lane];
    #pragma unroll 4
    for (int k = 0; k < HID; ++k) {
        float v = row[k];
        p0 += v * Wfc[k * PRED + lane];
        p1 += v * Wfc[k * PRED + 64 + lane];
    }
    float part = p0 * Wout[lane] + p1 * Wout[64 + lane];
    #pragma unroll
    for (int off = 32; off > 0; off >>= 1) part += __shfl_xor(part, off);
    if (lane == 0) out[g] = part + bout[0];
}

extern "C" void kernel_launch(void* const* d_in, const int* in_sizes, int n_in,
                              void* d_out, int out_size, void* d_ws, size_t ws_size,
                              hipStream_t stream) {
    const float* x         = (const float*)d_in[0];
    const float* edge_attr = (const float*)d_in[1];
    const int*   src       = (const int*)d_in[2];
    const int*   dst       = (const int*)d_in[3];
    const int*   gidx      = (const int*)d_in[4];
    const float* W_embed   = (const float*)d_in[6];
    const float* b_embed   = (const float*)d_in[7];
    const float* W_sig     = (const float*)d_in[8];
    const float* b_sig     = (const float*)d_in[9];
    const float* W_sp      = (const float*)d_in[10];
    const float* b_sp      = (const float*)d_in[11];
    const float* bn_gamma  = (const float*)d_in[12];
    const float* bn_beta   = (const float*)d_in[13];
    const float* W_fc      = (const float*)d_in[14];
    const float* b_fc      = (const float*)d_in[15];
    const float* W_out     = (const float*)d_in[16];
    const float* b_out     = (const float*)d_in[17];
    float* out = (float*)d_out;

    const size_t NH = (size_t)N_NODES * HID;
    float* ws     = (float*)d_ws;
    float* A      = ws;                                   // NH f32
    u32*   pA     = (u32*)(A + NH);                       // NH u32 (bf16x2)
    u32*   pB     = pA + NH;                              // NH u32
    u32*   eapS   = pB + NH;                              // (E+18)*24 u32 (f16, dst-sorted, 96B rows)
    int*   srcS   = (int*)(eapS + (size_t)(N_EDGES + 18) * ROW_U32);  // E+16 (padded)
    int*   iperm  = srcS + N_EDGES + 16;                  // E
    int*   rowptr = iperm + N_EDGES;                      // N+1
    int*   deg    = rowptr + N_NODES + 1;                 // N
    int*   cursor = deg + N_NODES;                        // N
    int*   partial    = cursor + N_NODES;                 // 256
    int*   partialExc = partial + 256;                    // 256
    f16*   Wf16   = (f16*)(partialExc + 256);             // 3*2*8*64*8 f16 = 48 KB
    f16*   Wp2    = Wf16 + 3 * 2 * 8 * 64 * 8;            // 3*2*16*64*8 f16 = 96 KB
    float* stats  = (float*)(Wp2 + 3 * 2 * 16 * 64 * 8);  // 3 * 4096 f32
    float* gf     = stats + 3 * 4096;                     // G*HID

    k_embed<<<512, 256, 0, stream>>>(x, W_embed, b_embed, A);

    // ---- CSR build + packs (once per call) ----
    k_zeroi<<<(2 * N_NODES + 255) / 256, 256, 0, stream>>>(deg, 2 * N_NODES);  // deg+cursor
    k_hist<<<(N_EDGES + 255) / 256, 256, 0, stream>>>(dst, deg);
    k_scanA<<<SCAN_BLOCKS, 256, 0, stream>>>(deg, partial);
    k_scanB<<<1, 256, 0, stream>>>(partial, partialExc, rowptr);
    k_scanC<<<SCAN_BLOCKS, 256, 0, stream>>>(deg, partialExc, rowptr);
    k_wprep<<<12, 256, 0, stream>>>(W_sig, W_sp, Wf16);
    k_wprep2<<<24, 256, 0, stream>>>(W_sig, W_sp, Wp2);
    k_rank<<<(N_EDGES + 16 + 255) / 256, 256, 0, stream>>>(dst, src, rowptr, cursor, srcS, iperm);
    k_epackS<<<4096, 256, 0, stream>>>(edge_attr, iperm, eapS);

    for (int i = 0; i < 3; ++i) {
        const float* stPrev = stats + (size_t)(i > 0 ? i - 1 : 0) * 4096;
        const float* gP     = bn_gamma + (i > 0 ? i - 1 : 0) * HID;
        const float* bP     = bn_beta + (i > 0 ? i - 1 : 0) * HID;
        float* stOut        = stats + (size_t)i * 4096;
        int applyBN = (i > 0) ? 1 : 0;
        k_projm<<<512, 256, 0, stream>>>(A, stPrev, gP, bP, applyBN,
                                         Wp2 + (size_t)i * 2 * 16 * 64 * 8,
                                         b_sig + i * HID, b_sp + i * HID,
                                         pA, pB, stOut);
        k_nodeagg<<<2048, 256, 0, stream>>>(A, stPrev, gP, bP, applyBN,
                                            pA, pB, eapS, srcS, rowptr,
                                            Wf16 + (size_t)i * 2 * 8 * 64 * 8,
                                            A, stOut);
    }

    k_zerof<<<(N_GRAPHS * HID + 255) / 256, 256, 0, stream>>>(gf, N_GRAPHS * HID);
    k_poolbn<<<256, 256, 0, stream>>>(A, stats + 2 * 4096, bn_gamma + 2 * HID,
                                      bn_beta + 2 * HID, gidx, gf);
    k_readout<<<(N_GRAPHS + 3) / 4, 256, 0, stream>>>(gf, W_fc, b_fc, W_out, b_out, out);
}

// Round 7
// 554.168 us; speedup vs baseline: 1.5916x; 1.1686x over previous
//
#include <hip/hip_runtime.h>

#define N_NODES 50000
#define N_EDGES 600000
#define N_GRAPHS 500
#define IN_F 92
#define HID 64
#define EDGE_F 41
#define ZDIM 169
#define PRED 128
#define BN_EPS 1e-5f
#define SCAN_BLOCKS 196          // ceil(50000/256)
#define ROW_U32 24               // eapS row = 48 f16 = 96 B
#define LOG2E 1.4426950408889634f
#define LN2   0.6931471805599453f

typedef unsigned int u32;
typedef _Float16 f16;
typedef _Float16 f16x2 __attribute__((ext_vector_type(2)));
typedef _Float16 f16x8 __attribute__((ext_vector_type(8)));
typedef float f32x4 __attribute__((ext_vector_type(4)));

// f32 -> bf16 round-to-nearest-even
__device__ __forceinline__ u32 f2bf(float f) {
    u32 u = __float_as_uint(f);
    return (u + 0x7fffu + ((u >> 16) & 1u)) >> 16;
}

// first idx in [0, nelem) with a[idx] >= val (a sorted ascending)
__device__ __forceinline__ int lbound(const int* __restrict__ a, int nelem, int val) {
    int lo = 0, hi = nelem;
    while (lo < hi) {
        int m = (lo + hi) >> 1;
        if (a[m] < val) lo = m + 1; else hi = m;
    }
    return lo;
}

// ---------------- CSR build ----------------
__global__ void k_zeroAll(int* __restrict__ ip, int n1, float* __restrict__ fp, int n2) {
    int i = blockIdx.x * 256 + threadIdx.x;
    if (i < n1) ip[i] = 0;
    else if (i - n1 < n2) fp[i - n1] = 0.f;
}

__global__ void k_hist(const int* __restrict__ dst, int* __restrict__ deg) {
    int e = blockIdx.x * 256 + threadIdx.x;
    if (e < N_EDGES) atomicAdd(&deg[dst[e]], 1);
}

__global__ __launch_bounds__(256) void k_scanA(const int* __restrict__ deg,
                                               int* __restrict__ partial) {
    __shared__ int s[256];
    int i = blockIdx.x * 256 + threadIdx.x;
    s[threadIdx.x] = (i < N_NODES) ? deg[i] : 0;
    __syncthreads();
    for (int off = 128; off > 0; off >>= 1) {
        if (threadIdx.x < off) s[threadIdx.x] += s[threadIdx.x + off];
        __syncthreads();
    }
    if (threadIdx.x == 0) partial[blockIdx.x] = s[0];
}

__global__ __launch_bounds__(256) void k_scanB(const int* __restrict__ partial,
                                               int* __restrict__ partialExc,
                                               int* __restrict__ rowptr) {
    __shared__ int s[256];
    int t = threadIdx.x;
    int v = (t < SCAN_BLOCKS) ? partial[t] : 0;
    s[t] = v;
    __syncthreads();
    for (int off = 1; off < 256; off <<= 1) {
        int x = (t >= off) ? s[t - off] : 0;
        __syncthreads();
        s[t] += x;
        __syncthreads();
    }
    partialExc[t] = s[t] - v;
    if (t == 0) rowptr[N_NODES] = N_EDGES;
}

__global__ __launch_bounds__(256) void k_scanC(const int* __restrict__ deg,
                                               const int* __restrict__ partialExc,
                                               int* __restrict__ rowptr) {
    __shared__ int s[256];
    int i = blockIdx.x * 256 + threadIdx.x;
    int t = threadIdx.x;
    int v = (i < N_NODES) ? deg[i] : 0;
    s[t] = v;
    __syncthreads();
    for (int off = 1; off < 256; off <<= 1) {
        int x = (t >= off) ? s[t - off] : 0;
        __syncthreads();
        s[t] += x;
        __syncthreads();
    }
    if (i < N_NODES) rowptr[i] = s[t] - v + partialExc[blockIdx.x];
}

// ---------------- rank: CSR slot assignment (perm only); pads srcS tail ------
__global__ void k_rank(const int* __restrict__ dst, const int* __restrict__ src,
                       const int* __restrict__ rowptr, int* __restrict__ cursor,
                       int* __restrict__ srcS, int* __restrict__ iperm) {
    int e = blockIdx.x * 256 + threadIdx.x;
    if (e >= N_EDGES) {
        if (e < N_EDGES + 32) srcS[e] = 0;   // pad: prefetch reads stay in-bounds
        return;
    }
    int d = dst[e];
    int p = rowptr[d] + atomicAdd(&cursor[d], 1);
    srcS[p] = src[e];
    iperm[p] = e;
}

// ---------------- epackS: gather-permute ea rows -> f16, 96 B rows ----------
__global__ __launch_bounds__(256) void k_epackS(const float* __restrict__ ea,
                                                const int* __restrict__ iperm,
                                                u32* __restrict__ eapS) {
    const int total = N_EDGES * ROW_U32;
    const int stride = gridDim.x * 256;
    for (int idx = blockIdx.x * 256 + threadIdx.x; idx < total; idx += stride) {
        int p = idx / ROW_U32;
        int q = idx - p * ROW_U32;
        int e = iperm[p];
        int k0 = 2 * q, k1 = k0 + 1;
        float f0 = (k0 < EDGE_F) ? ea[(size_t)e * EDGE_F + k0] : 0.f;
        float f1 = (k1 < EDGE_F) ? ea[(size_t)e * EDGE_F + k1] : 0.f;
        f16x2 hv = {(f16)f0, (f16)f1};
        eapS[idx] = __builtin_bit_cast(u32, hv);
    }
}

// ---------------- wprepAll: all weight prep in one launch --------------------
// job1 t in [0,3072): edge W -> Wf16[L][kt<2][jt<8][lane][8], SCALED by LOG2E
// job2 t in [3072,9216): proj W -> Wp2[L][kt<2][jt<16][lane][8]
// job3 t in [9216,9984): embed W -> Wef[kt<3][jt<4][lane][8]
__global__ void k_wprepAll(const float* __restrict__ Wsig, const float* __restrict__ Wsp,
                           const float* __restrict__ Wemb,
                           f16* __restrict__ Wf16, f16* __restrict__ Wp2,
                           f16* __restrict__ Wef) {
    int t = blockIdx.x * 256 + threadIdx.x;
    if (t < 3072) {
        int lane = t & 63;
        int jt = (t >> 6) & 7;
        int kt = (t >> 9) & 1;
        int L = t >> 10;
        int j128 = jt * 16 + (lane & 15);
        const float* Wbase = (j128 < 64) ? Wsig : Wsp;
        int j = j128 & 63;
        f16x8 v;
        #pragma unroll
        for (int b = 0; b < 8; ++b) {
            int k = kt * 32 + (lane >> 4) * 8 + b;
            float f = (k < EDGE_F) ? Wbase[(size_t)L * ZDIM * HID + (128 + k) * HID + j] * LOG2E : 0.f;
            v[b] = (f16)f;
        }
        *(f16x8*)(Wf16 + ((size_t)((L * 2 + kt) * 8 + jt) * 64 + lane) * 8) = v;
    } else if (t < 9216) {
        int t2 = t - 3072;
        int lane = t2 & 63;
        int jt = (t2 >> 6) & 15;
        int kt = (t2 >> 10) & 1;
        int L = t2 >> 11;
        int j256 = jt * 16 + (lane & 15);
        const float* Wbase = (j256 & 64) ? Wsp : Wsig;
        int rowoff = (j256 & 128) ? 64 : 0;
        int j = j256 & 63;
        f16x8 v;
        #pragma unroll
        for (int b = 0; b < 8; ++b) {
            int k = kt * 32 + (lane >> 4) * 8 + b;
            v[b] = (f16)Wbase[(size_t)L * ZDIM * HID + (rowoff + k) * HID + j];
        }
        *(f16x8*)(Wp2 + ((size_t)((L * 2 + kt) * 16 + jt) * 64 + lane) * 8) = v;
    } else if (t < 9984) {
        int t3 = t - 9216;
        int lane = t3 & 63;
        int jt = (t3 >> 6) & 3;
        int kt = t3 >> 8;    // 0..2
        int j = jt * 16 + (lane & 15);
        f16x8 v;
        #pragma unroll
        for (int b = 0; b < 8; ++b) {
            int k = kt * 32 + (lane >> 4) * 8 + b;
            v[b] = (k < IN_F) ? (f16)Wemb[(size_t)k * HID + j] : (f16)0.f;
        }
        *(f16x8*)(Wef + ((size_t)(kt * 4 + jt) * 64 + lane) * 8) = v;
    }
}

// ---------------- embedm: A = x @ W_embed + b via MFMA ----------------------
__global__ __launch_bounds__(256) void k_embedm(const float* __restrict__ x,
                                                const f16* __restrict__ Wef,
                                                const float* __restrict__ b,
                                                float* __restrict__ A) {
    __shared__ f16x8 Wl[12 * 64];   // 12 KB
    for (int i = threadIdx.x; i < 12 * 64; i += 256) Wl[i] = ((const f16x8*)Wef)[i];
    __syncthreads();
    const int lane = threadIdx.x & 63;
    const int col = lane & 15, grp = lane >> 4;
    float bj[4];
    #pragma unroll
    for (int jt = 0; jt < 4; ++jt) bj[jt] = b[jt * 16 + col];
    const int wid = blockIdx.x * 4 + (threadIdx.x >> 6);
    const int nw = gridDim.x * 4;
    for (int c = wid; c < N_NODES / 16; c += nw) {
        const int node = c * 16 + col;
        const float* xr = x + (size_t)node * IN_F;
        f16x8 af[3];
        #pragma unroll
        for (int kt = 0; kt < 3; ++kt) {
            int base = kt * 32 + grp * 8;
            float4 v0 = *(const float4*)(xr + base);          // base<=88 -> 88..91 valid
            float4 v1 = (base + 4 < IN_F) ? *(const float4*)(xr + base + 4)
                                          : make_float4(0.f, 0.f, 0.f, 0.f);
            af[kt] = f16x8{(f16)v0.x, (f16)v0.y, (f16)v0.z, (f16)v0.w,
                           (f16)v1.x, (f16)v1.y, (f16)v1.z, (f16)v1.w};
        }
        #pragma unroll
        for (int jt = 0; jt < 4; ++jt) {
            f32x4 c4 = {};
            c4 = __builtin_amdgcn_mfma_f32_16x16x32_f16(af[0], Wl[(0 * 4 + jt) * 64 + lane], c4, 0, 0, 0);
            c4 = __builtin_amdgcn_mfma_f32_16x16x32_f16(af[1], Wl[(1 * 4 + jt) * 64 + lane], c4, 0, 0, 0);
            c4 = __builtin_amdgcn_mfma_f32_16x16x32_f16(af[2], Wl[(2 * 4 + jt) * 64 + lane], c4, 0, 0, 0);
            #pragma unroll
            for (int r = 0; r < 4; ++r)
                A[(size_t)(c * 16 + grp * 4 + r) * HID + jt * 16 + col] = c4[r] + bj[jt];
        }
    }
}

// ---------------- projm: MFMA node projections (BN fused, LOG2E-scaled pack) -
__global__ __launch_bounds__(256, 4) void k_projm(const float* __restrict__ A,
                                                  const float* __restrict__ statsPrev,
                                                  const float* __restrict__ gammaP,
                                                  const float* __restrict__ betaP,
                                                  int applyBN,
                                                  const f16* __restrict__ Wp2L,
                                                  const float* __restrict__ bsig,
                                                  const float* __restrict__ bsp,
                                                  u32* __restrict__ pA,
                                                  u32* __restrict__ pB,
                                                  float* __restrict__ statsOut) {
    __shared__ f16x8 Wl[32 * 64];   // 32 KB
    for (int i = threadIdx.x; i < 32 * 64; i += 256) Wl[i] = ((const f16x8*)Wp2L)[i];
    if (blockIdx.x == 0)
        for (int i = threadIdx.x; i < 128 * 32; i += 256) statsOut[i] = 0.f;
    __syncthreads();
    const int lane = threadIdx.x & 63;
    const int col = lane & 15;
    float sck[2][8], shk[2][8];
    #pragma unroll
    for (int kt = 0; kt < 2; ++kt)
        #pragma unroll
        for (int b = 0; b < 8; ++b) {
            int k = kt * 32 + (lane >> 4) * 8 + b;
            float scv = 1.f, shv = 0.f;
            if (applyBN) {
                float m = statsPrev[k * 32] * (1.f / N_NODES);
                float v = statsPrev[(64 + k) * 32] * (1.f / N_NODES) - m * m;
                scv = rsqrtf(v + BN_EPS) * gammaP[k];
                shv = betaP[k] - m * scv;
            }
            sck[kt][b] = scv;
            shk[kt][b] = shv;
        }
    float bAs[4], bPs[4];
    #pragma unroll
    for (int jt = 0; jt < 4; ++jt) {
        bAs[jt] = bsig[jt * 16 + col] * LOG2E;
        bPs[jt] = bsp[jt * 16 + col] * LOG2E;
    }
    const int wid = blockIdx.x * 4 + (threadIdx.x >> 6);
    const int nw = gridDim.x * 4;
    for (int c = wid; c < N_NODES / 16; c += nw) {
        const int node = c * 16 + col;
        const float4* Arow = (const float4*)(A + (size_t)node * HID);
        f16x8 af[2];
        #pragma unroll
        for (int kt = 0; kt < 2; ++kt) {
            float4 v0 = Arow[kt * 8 + (lane >> 4) * 2];
            float4 v1 = Arow[kt * 8 + (lane >> 4) * 2 + 1];
            float e0 = v0.x * sck[kt][0] + shk[kt][0];
            float e1 = v0.y * sck[kt][1] + shk[kt][1];
            float e2 = v0.z * sck[kt][2] + shk[kt][2];
            float e3 = v0.w * sck[kt][3] + shk[kt][3];
            float e4 = v1.x * sck[kt][4] + shk[kt][4];
            float e5 = v1.y * sck[kt][5] + shk[kt][5];
            float e6 = v1.z * sck[kt][6] + shk[kt][6];
            float e7 = v1.w * sck[kt][7] + shk[kt][7];
            af[kt] = f16x8{(f16)e0, (f16)e1, (f16)e2, (f16)e3,
                           (f16)e4, (f16)e5, (f16)e6, (f16)e7};
        }
        #pragma unroll
        for (int h = 0; h < 2; ++h) {
            f32x4 c4[8];
            #pragma unroll
            for (int jt2 = 0; jt2 < 8; ++jt2) {
                int jt = h * 8 + jt2;
                f32x4 acc = {};
                acc = __builtin_amdgcn_mfma_f32_16x16x32_f16(af[0], Wl[(0 * 16 + jt) * 64 + lane], acc, 0, 0, 0);
                c4[jt2] = __builtin_amdgcn_mfma_f32_16x16x32_f16(af[1], Wl[(1 * 16 + jt) * 64 + lane], acc, 0, 0, 0);
            }
            u32* dstArr = h ? pB : pA;
            #pragma unroll
            for (int jt2 = 0; jt2 < 4; ++jt2)
                #pragma unroll
                for (int r = 0; r < 4; ++r) {
                    float s = fmaf(c4[jt2][r], LOG2E, h ? 0.f : bAs[jt2]);
                    float p = fmaf(c4[jt2 + 4][r], LOG2E, h ? 0.f : bPs[jt2]);
                    int n2 = c * 16 + (lane >> 4) * 4 + r;
                    dstArr[(size_t)n2 * HID + jt2 * 16 + col] = f2bf(s) | (f2bf(p) << 16);
                }
        }
    }
}

// ---------------- nodeagg: MFMA tiles + 1-node-deep software pipeline --------
__global__ __launch_bounds__(256) void k_nodeagg(const float* __restrict__ A,
                                                 const float* __restrict__ statsPrev,
                                                 const float* __restrict__ gammaP,
                                                 const float* __restrict__ betaP,
                                                 int applyBN,
                                                 const u32* __restrict__ pAv,
                                                 const u32* __restrict__ pBv,
                                                 const u32* __restrict__ eapS,
                                                 const int* __restrict__ srcS,
                                                 const int* __restrict__ rowptr,
                                                 const f16* __restrict__ Wf16L,
                                                 float* __restrict__ Aout,
                                                 float* __restrict__ statsOut) {
    const int lane = threadIdx.x & 63;
    const int col = lane & 15;
    const int grp = lane >> 4;
    const int rowb = grp * 4;

    const f16x8* WfL = (const f16x8*)Wf16L;
    f16x8 bfrag[2][8];
    #pragma unroll
    for (int kt = 0; kt < 2; ++kt)
        #pragma unroll
        for (int jt = 0; jt < 8; ++jt)
            bfrag[kt][jt] = WfL[(kt * 8 + jt) * 64 + lane];

    float scL = 1.f, shL = 0.f;
    if (applyBN) {
        float m = statsPrev[lane * 32] * (1.f / N_NODES);
        float v = statsPrev[(64 + lane) * 32] * (1.f / N_NODES) - m * m;
        scL = rsqrtf(v + BN_EPS) * gammaP[lane];
        shL = betaP[lane] - m * scL;
    }

    const int nwaves = gridDim.x << 2;
    const int w = (blockIdx.x << 2) + (threadIdx.x >> 6);
    const int T = (N_EDGES + 1 + nwaves - 1) / nwaves;
    int nb = min(lbound(rowptr, N_NODES + 1, w * T), N_NODES);
    int ne = min(lbound(rowptr, N_NODES + 1, w * T + T), N_NODES);

    float lsum = 0.f, lsq = 0.f;
    if (nb < ne) {
        // pipeline prologue: node nb state
        int rb = rowptr[nb];
        int re = rowptr[nb + 1];
        float resid = A[(size_t)nb * HID + lane];
        if (applyBN) resid = resid * scL + shL;
        u32 pb4[4];
        #pragma unroll
        for (int jt = 0; jt < 4; ++jt) pb4[jt] = pBv[(size_t)nb * HID + jt * 16 + col];
        int s0 = srcS[rb + rowb + 0], s1 = srcS[rb + rowb + 1],
            s2 = srcS[rb + rowb + 2], s3 = srcS[rb + rowb + 3];

        for (int n = nb; n < ne; ++n) {
            // prefetch node n+1 (clamped; unused on last iter)
            const int nn = (n + 1 < N_NODES) ? n + 1 : n;
            const int re_nx = rowptr[nn + 1];
            float resid_nx = A[(size_t)nn * HID + lane];
            if (applyBN) resid_nx = resid_nx * scL + shL;
            u32 pbx[4];
            #pragma unroll
            for (int jt = 0; jt < 4; ++jt) pbx[jt] = pBv[(size_t)nn * HID + jt * 16 + col];

            float bsigj[4], bspj[4];
            #pragma unroll
            for (int jt = 0; jt < 4; ++jt) {
                bsigj[jt] = __uint_as_float(pb4[jt] << 16);
                bspj[jt]  = __uint_as_float(pb4[jt] & 0xffff0000u);
            }
            float accv[4] = {0.f, 0.f, 0.f, 0.f};
            for (int et = rb; et < re; et += 16) {
                const int cnt = re - et;
                // gathers from prefetched srcS
                u32 ga[4][4];
                #pragma unroll
                for (int jt = 0; jt < 4; ++jt) {
                    ga[jt][0] = pAv[(size_t)s0 * HID + jt * 16 + col];
                    ga[jt][1] = pAv[(size_t)s1 * HID + jt * 16 + col];
                    ga[jt][2] = pAv[(size_t)s2 * HID + jt * 16 + col];
                    ga[jt][3] = pAv[(size_t)s3 * HID + jt * 16 + col];
                }
                const f16x8* arow = (const f16x8*)(eapS + (size_t)(et + col) * ROW_U32);
                f16x8 a0 = arow[grp];
                f16x8 a1 = arow[4 + grp];   // overruns row into zero-weight k: harmless
                // prefetch srcS for next tile (or next node's first tile: re == its rb)
                const int nxt = (et + 16 < re) ? et + 16 : re;
                const int t0n = srcS[nxt + rowb + 0], t1n = srcS[nxt + rowb + 1],
                          t2n = srcS[nxt + rowb + 2], t3n = srcS[nxt + rowb + 3];
                #pragma unroll
                for (int jt = 0; jt < 4; ++jt) {
                    f32x4 cs = {}, cp = {};
                    cs = __builtin_amdgcn_mfma_f32_16x16x32_f16(a0, bfrag[0][jt], cs, 0, 0, 0);
                    cs = __builtin_amdgcn_mfma_f32_16x16x32_f16(a1, bfrag[1][jt], cs, 0, 0, 0);
                    cp = __builtin_amdgcn_mfma_f32_16x16x32_f16(a0, bfrag[0][jt + 4], cp, 0, 0, 0);
                    cp = __builtin_amdgcn_mfma_f32_16x16x32_f16(a1, bfrag[1][jt + 4], cp, 0, 0, 0);
                    #pragma unroll
                    for (int r = 0; r < 4; ++r) {
                        float s_ = cs[r] + __uint_as_float(ga[jt][r] << 16) + bsigj[jt];
                        float p_ = cp[r] + __uint_as_float(ga[jt][r] & 0xffff0000u) + bspj[jt];
                        float g_ = __builtin_amdgcn_rcpf(1.f + exp2f(-s_));
                        float m_ = fmaxf(p_, 0.f) + log2f(1.f + exp2f(-fabsf(p_)));
                        accv[jt] += (rowb + r < cnt) ? g_ * m_ : 0.f;
                    }
                }
                s0 = t0n; s1 = t1n; s2 = t2n; s3 = t3n;
            }
            // deg-0 node: tile loop skipped; s0..s3 already == srcS[re..] (rb==re)
            #pragma unroll
            for (int jt = 0; jt < 4; ++jt) {
                accv[jt] += __shfl_xor(accv[jt], 16);
                accv[jt] += __shfl_xor(accv[jt], 32);
            }
            float accSel = (lane & 32) ? ((lane & 16) ? accv[3] : accv[2])
                                       : ((lane & 16) ? accv[1] : accv[0]);
            float outv = resid + accSel * LN2;
            Aout[(size_t)n * HID + lane] = outv;
            lsum += outv;
            lsq += outv * outv;
            // rotate pipeline registers
            rb = re; re = re_nx; resid = resid_nx;
            pb4[0] = pbx[0]; pb4[1] = pbx[1]; pb4[2] = pbx[2]; pb4[3] = pbx[3];
        }
    }

    __shared__ float redS[256], redQ[256];
    redS[threadIdx.x] = lsum;
    redQ[threadIdx.x] = lsq;
    __syncthreads();
    if (threadIdx.x < 64) {
        float s = redS[threadIdx.x] + redS[threadIdx.x + 64] + redS[threadIdx.x + 128] + redS[threadIdx.x + 192];
        float q = redQ[threadIdx.x] + redQ[threadIdx.x + 64] + redQ[threadIdx.x + 128] + redQ[threadIdx.x + 192];
        unsafeAtomicAdd(&statsOut[threadIdx.x * 32], s);
        unsafeAtomicAdd(&statsOut[(64 + threadIdx.x) * 32], q);
    }
}

// ---------------- pool (+ final BN): segment-sum over sorted graph_idx ------
__global__ __launch_bounds__(256) void k_poolbn(const float* __restrict__ A,
                                                const float* __restrict__ stats,
                                                const float* __restrict__ gamma,
                                                const float* __restrict__ beta,
                                                const int* __restrict__ gidx,
                                                float* __restrict__ gf) {
    const int lane = threadIdx.x & 63;
    float m = stats[lane * 32] * (1.f / N_NODES);
    float v = stats[(64 + lane) * 32] * (1.f / N_NODES) - m * m;
    float scv = rsqrtf(v + BN_EPS) * gamma[lane];
    float shv = beta[lane] - m * scv;
    const int wid = blockIdx.x * 4 + (threadIdx.x >> 6);
    const int nwaves = gridDim.x * 4;
    const int chunk = (N_NODES + nwaves - 1) / nwaves;
    int r0 = wid * chunk;
    if (r0 >= N_NODES) return;
    int r1 = min(r0 + chunk, N_NODES);
    int gcur = gidx[r0];
    float acc = 0.f;
    for (int r = r0; r < r1; ++r) {
        int g = gidx[r];
        if (g != gcur) {
            unsafeAtomicAdd(&gf[(size_t)gcur * HID + lane], acc);
            acc = 0.f;
            gcur = g;
        }
        acc += A[(size_t)r * HID + lane] * scv + shv;
    }
    unsafeAtomicAdd(&gf[(size_t)gcur * HID + lane], acc);
}

// ---------------- readout ----------------
__global__ __launch_bounds__(256) void k_readout(const float* __restrict__ gf,
                                                 const float* __restrict__ Wfc,
                                                 const float* __restrict__ bfc,
                                                 const float* __restrict__ Wout,
                                                 const float* __restrict__ bout,
                                                 float* __restrict__ out) {
    const int lane = threadIdx.x & 63;
    const int g = blockIdx.x * 4 + (threadIdx.x >> 6);
    if (g >= N_GRAPHS) return;
    const float* row = gf + (size_t)g * HID;
    float p0 = bfc[lane], p1 = bfc[64 + lane];
    #pragma unroll 4
    for (int k = 0; k < HID; ++k) {
        float v = row[k];
        p0 += v * Wfc[k * PRED + lane];
        p1 += v * Wfc[k * PRED + 64 + lane];
    }
    float part = p0 * Wout[lane] + p1 * Wout[64 + lane];
    #pragma unroll
    for (int off = 32; off > 0; off >>= 1) part += __shfl_xor(part, off);
    if (lane == 0) out[g] = part + bout[0];
}

extern "C" void kernel_launch(void* const* d_in, const int* in_sizes, int n_in,
                              void* d_out, int out_size, void* d_ws, size_t ws_size,
                              hipStream_t stream) {
    const float* x         = (const float*)d_in[0];
    const float* edge_attr = (const float*)d_in[1];
    const int*   src       = (const int*)d_in[2];
    const int*   dst       = (const int*)d_in[3];
    const int*   gidx      = (const int*)d_in[4];
    const float* W_embed   = (const float*)d_in[6];
    const float* b_embed   = (const float*)d_in[7];
    const float* W_sig     = (const float*)d_in[8];
    const float* b_sig     = (const float*)d_in[9];
    const float* W_sp      = (const float*)d_in[10];
    const float* b_sp      = (const float*)d_in[11];
    const float* bn_gamma  = (const float*)d_in[12];
    const float* bn_beta   = (const float*)d_in[13];
    const float* W_fc      = (const float*)d_in[14];
    const float* b_fc      = (const float*)d_in[15];
    const float* W_out     = (const float*)d_in[16];
    const float* b_out     = (const float*)d_in[17];
    float* out = (float*)d_out;

    const size_t NH = (size_t)N_NODES * HID;
    float* ws     = (float*)d_ws;
    float* A      = ws;                                   // NH f32
    u32*   pA     = (u32*)(A + NH);                       // NH u32 (bf16x2, LOG2E-scaled)
    u32*   pB     = pA + NH;                              // NH u32
    u32*   eapS   = pB + NH;                              // (E+32)*24 u32
    int*   srcS   = (int*)(eapS + (size_t)(N_EDGES + 32) * ROW_U32);  // E+32 (padded)
    int*   iperm  = srcS + N_EDGES + 32;                  // E
    int*   rowptr = iperm + N_EDGES;                      // N+1
    int*   deg    = rowptr + N_NODES + 1;                 // N
    int*   cursor = deg + N_NODES;                        // N
    int*   partial    = cursor + N_NODES;                 // 256
    int*   partialExc = partial + 256;                    // 256
    f16*   Wf16   = (f16*)(partialExc + 256);             // 3*2*8*64*8 f16
    f16*   Wp2    = Wf16 + 3 * 2 * 8 * 64 * 8;            // 3*2*16*64*8 f16
    f16*   Wef    = Wp2 + 3 * 2 * 16 * 64 * 8;            // 3*4*64*8 f16
    float* stats  = (float*)(Wef + 3 * 4 * 64 * 8);       // 3 * 4096 f32
    float* gf     = stats + 3 * 4096;                     // G*HID

    // ---- prep: weights, zeros, CSR (once per call) ----
    k_wprepAll<<<39, 256, 0, stream>>>(W_sig, W_sp, W_embed, Wf16, Wp2, Wef);
    k_zeroAll<<<(2 * N_NODES + N_GRAPHS * HID + 255) / 256, 256, 0, stream>>>(
        deg, 2 * N_NODES, gf, N_GRAPHS * HID);
    k_hist<<<(N_EDGES + 255) / 256, 256, 0, stream>>>(dst, deg);
    k_scanA<<<SCAN_BLOCKS, 256, 0, stream>>>(deg, partial);
    k_scanB<<<1, 256, 0, stream>>>(partial, partialExc, rowptr);
    k_scanC<<<SCAN_BLOCKS, 256, 0, stream>>>(deg, partialExc, rowptr);
    k_rank<<<(N_EDGES + 32 + 255) / 256, 256, 0, stream>>>(dst, src, rowptr, cursor, srcS, iperm);
    k_embedm<<<512, 256, 0, stream>>>(x, Wef, b_embed, A);
    k_epackS<<<4096, 256, 0, stream>>>(edge_attr, iperm, eapS);

    for (int i = 0; i < 3; ++i) {
        const float* stPrev = stats + (size_t)(i > 0 ? i - 1 : 0) * 4096;
        const float* gP     = bn_gamma + (i > 0 ? i - 1 : 0) * HID;
        const float* bP     = bn_beta + (i > 0 ? i - 1 : 0) * HID;
        float* stOut        = stats + (size_t)i * 4096;
        int applyBN = (i > 0) ? 1 : 0;
        k_projm<<<512, 256, 0, stream>>>(A, stPrev, gP, bP, applyBN,
                                         Wp2 + (size_t)i * 2 * 16 * 64 * 8,
                                         b_sig + i * HID, b_sp + i * HID,
                                         pA, pB, stOut);
        k_nodeagg<<<2048, 256, 0, stream>>>(A, stPrev, gP, bP, applyBN,
                                            pA, pB, eapS, srcS, rowptr,
                                            Wf16 + (size_t)i * 2 * 8 * 64 * 8,
                                            A, stOut);
    }

    k_poolbn<<<256, 256, 0, stream>>>(A, stats + 2 * 4096, bn_gamma + 2 * HID,
                                      bn_beta + 2 * HID, gidx, gf);
    k_readout<<<(N_GRAPHS + 3) / 4, 256, 0, stream>>>(gf, W_fc, b_fc, W_out, b_out, out);
}

// Round 8
// 528.931 us; speedup vs baseline: 1.6676x; 1.0477x over previous
//
#include <hip/hip_runtime.h>

#define N_NODES 50000
#define N_EDGES 600000
#define N_GRAPHS 500
#define IN_F 92
#define HID 64
#define EDGE_F 41
#define ZDIM 169
#define PRED 128
#define BN_EPS 1e-5f
#define SCAN_BLOCKS 196          // ceil(50000/256)
#define ROW_U32 24               // eapS row = 48 f16 = 96 B
#define LOG2E 1.4426950408889634f
#define LN2   0.6931471805599453f
#define NAGG_BLOCKS 2048
#define NW2 (NAGG_BLOCKS * 8)    // 4 waves/block x 2 contexts
#define PART_T ((N_EDGES + 1 + NW2 - 1) / NW2)

typedef unsigned int u32;
typedef _Float16 f16;
typedef _Float16 f16x2 __attribute__((ext_vector_type(2)));
typedef _Float16 f16x8 __attribute__((ext_vector_type(8)));
typedef float f32x4 __attribute__((ext_vector_type(4)));

// f32 -> bf16 round-to-nearest-even
__device__ __forceinline__ u32 f2bf(float f) {
    u32 u = __float_as_uint(f);
    return (u + 0x7fffu + ((u >> 16) & 1u)) >> 16;
}

// first idx in [0, nelem) with a[idx] >= val (a sorted ascending)
__device__ __forceinline__ int lbound(const int* __restrict__ a, int nelem, int val) {
    int lo = 0, hi = nelem;
    while (lo < hi) {
        int m = (lo + hi) >> 1;
        if (a[m] < val) lo = m + 1; else hi = m;
    }
    return lo;
}

// ---------------- CSR build ----------------
__global__ void k_zeroAll(int* __restrict__ ip, int n1, float* __restrict__ fp, int n2) {
    int i = blockIdx.x * 256 + threadIdx.x;
    if (i < n1) ip[i] = 0;
    else if (i - n1 < n2) fp[i - n1] = 0.f;
}

__global__ void k_hist(const int* __restrict__ dst, int* __restrict__ deg) {
    int e = blockIdx.x * 256 + threadIdx.x;
    if (e < N_EDGES) atomicAdd(&deg[dst[e]], 1);
}

__global__ __launch_bounds__(256) void k_scanA(const int* __restrict__ deg,
                                               int* __restrict__ partial) {
    __shared__ int s[256];
    int i = blockIdx.x * 256 + threadIdx.x;
    s[threadIdx.x] = (i < N_NODES) ? deg[i] : 0;
    __syncthreads();
    for (int off = 128; off > 0; off >>= 1) {
        if (threadIdx.x < off) s[threadIdx.x] += s[threadIdx.x + off];
        __syncthreads();
    }
    if (threadIdx.x == 0) partial[blockIdx.x] = s[0];
}

__global__ __launch_bounds__(256) void k_scanB(const int* __restrict__ partial,
                                               int* __restrict__ partialExc,
                                               int* __restrict__ rowptr) {
    __shared__ int s[256];
    int t = threadIdx.x;
    int v = (t < SCAN_BLOCKS) ? partial[t] : 0;
    s[t] = v;
    __syncthreads();
    for (int off = 1; off < 256; off <<= 1) {
        int x = (t >= off) ? s[t - off] : 0;
        __syncthreads();
        s[t] += x;
        __syncthreads();
    }
    partialExc[t] = s[t] - v;
    if (t == 0) rowptr[N_NODES] = N_EDGES;
}

__global__ __launch_bounds__(256) void k_scanC(const int* __restrict__ deg,
                                               const int* __restrict__ partialExc,
                                               int* __restrict__ rowptr) {
    __shared__ int s[256];
    int i = blockIdx.x * 256 + threadIdx.x;
    int t = threadIdx.x;
    int v = (i < N_NODES) ? deg[i] : 0;
    s[t] = v;
    __syncthreads();
    for (int off = 1; off < 256; off <<= 1) {
        int x = (t >= off) ? s[t - off] : 0;
        __syncthreads();
        s[t] += x;
        __syncthreads();
    }
    if (i < N_NODES) rowptr[i] = s[t] - v + partialExc[blockIdx.x];
}

// ---------------- part: precompute wave-partition node boundaries ------------
__global__ void k_part(const int* __restrict__ rowptr, int* __restrict__ partW) {
    int i = blockIdx.x * 256 + threadIdx.x;
    if (i <= NW2) partW[i] = min(lbound(rowptr, N_NODES + 1, i * PART_T), N_NODES);
}

// ---------------- rank: CSR slot assignment (perm only); pads srcS tail ------
__global__ void k_rank(const int* __restrict__ dst, const int* __restrict__ src,
                       const int* __restrict__ rowptr, int* __restrict__ cursor,
                       int* __restrict__ srcS, int* __restrict__ iperm) {
    int e = blockIdx.x * 256 + threadIdx.x;
    if (e >= N_EDGES) {
        if (e < N_EDGES + 32) srcS[e] = 0;   // pad: prefetch reads stay in-bounds
        return;
    }
    int d = dst[e];
    int p = rowptr[d] + atomicAdd(&cursor[d], 1);
    srcS[p] = src[e];
    iperm[p] = e;
}

// ---------------- epackS: gather-permute ea rows -> f16, 96 B rows ----------
__global__ __launch_bounds__(256) void k_epackS(const float* __restrict__ ea,
                                                const int* __restrict__ iperm,
                                                u32* __restrict__ eapS) {
    const int total = N_EDGES * ROW_U32;
    const int stride = gridDim.x * 256;
    for (int idx = blockIdx.x * 256 + threadIdx.x; idx < total; idx += stride) {
        int p = idx / ROW_U32;
        int q = idx - p * ROW_U32;
        int e = iperm[p];
        int k0 = 2 * q, k1 = k0 + 1;
        float f0 = (k0 < EDGE_F) ? ea[(size_t)e * EDGE_F + k0] : 0.f;
        float f1 = (k1 < EDGE_F) ? ea[(size_t)e * EDGE_F + k1] : 0.f;
        f16x2 hv = {(f16)f0, (f16)f1};
        eapS[idx] = __builtin_bit_cast(u32, hv);
    }
}

// ---------------- wprepAll: all weight prep in one launch --------------------
__global__ void k_wprepAll(const float* __restrict__ Wsig, const float* __restrict__ Wsp,
                           const float* __restrict__ Wemb,
                           f16* __restrict__ Wf16, f16* __restrict__ Wp2,
                           f16* __restrict__ Wef) {
    int t = blockIdx.x * 256 + threadIdx.x;
    if (t < 3072) {
        int lane = t & 63;
        int jt = (t >> 6) & 7;
        int kt = (t >> 9) & 1;
        int L = t >> 10;
        int j128 = jt * 16 + (lane & 15);
        const float* Wbase = (j128 < 64) ? Wsig : Wsp;
        int j = j128 & 63;
        f16x8 v;
        #pragma unroll
        for (int b = 0; b < 8; ++b) {
            int k = kt * 32 + (lane >> 4) * 8 + b;
            float f = (k < EDGE_F) ? Wbase[(size_t)L * ZDIM * HID + (128 + k) * HID + j] * LOG2E : 0.f;
            v[b] = (f16)f;
        }
        *(f16x8*)(Wf16 + ((size_t)((L * 2 + kt) * 8 + jt) * 64 + lane) * 8) = v;
    } else if (t < 9216) {
        int t2 = t - 3072;
        int lane = t2 & 63;
        int jt = (t2 >> 6) & 15;
        int kt = (t2 >> 10) & 1;
        int L = t2 >> 11;
        int j256 = jt * 16 + (lane & 15);
        const float* Wbase = (j256 & 64) ? Wsp : Wsig;
        int rowoff = (j256 & 128) ? 64 : 0;
        int j = j256 & 63;
        f16x8 v;
        #pragma unroll
        for (int b = 0; b < 8; ++b) {
            int k = kt * 32 + (lane >> 4) * 8 + b;
            v[b] = (f16)Wbase[(size_t)L * ZDIM * HID + (rowoff + k) * HID + j];
        }
        *(f16x8*)(Wp2 + ((size_t)((L * 2 + kt) * 16 + jt) * 64 + lane) * 8) = v;
    } else if (t < 9984) {
        int t3 = t - 9216;
        int lane = t3 & 63;
        int jt = (t3 >> 6) & 3;
        int kt = t3 >> 8;    // 0..2
        int j = jt * 16 + (lane & 15);
        f16x8 v;
        #pragma unroll
        for (int b = 0; b < 8; ++b) {
            int k = kt * 32 + (lane >> 4) * 8 + b;
            v[b] = (k < IN_F) ? (f16)Wemb[(size_t)k * HID + j] : (f16)0.f;
        }
        *(f16x8*)(Wef + ((size_t)(kt * 4 + jt) * 64 + lane) * 8) = v;
    }
}

// ---------------- embedm: A = x @ W_embed + b via MFMA ----------------------
__global__ __launch_bounds__(256) void k_embedm(const float* __restrict__ x,
                                                const f16* __restrict__ Wef,
                                                const float* __restrict__ b,
                                                float* __restrict__ A) {
    __shared__ f16x8 Wl[12 * 64];   // 12 KB
    for (int i = threadIdx.x; i < 12 * 64; i += 256) Wl[i] = ((const f16x8*)Wef)[i];
    __syncthreads();
    const int lane = threadIdx.x & 63;
    const int col = lane & 15, grp = lane >> 4;
    float bj[4];
    #pragma unroll
    for (int jt = 0; jt < 4; ++jt) bj[jt] = b[jt * 16 + col];
    const int wid = blockIdx.x * 4 + (threadIdx.x >> 6);
    const int nw = gridDim.x * 4;
    for (int c = wid; c < N_NODES / 16; c += nw) {
        const int node = c * 16 + col;
        const float* xr = x + (size_t)node * IN_F;
        f16x8 af[3];
        #pragma unroll
        for (int kt = 0; kt < 3; ++kt) {
            int base = kt * 32 + grp * 8;
            float4 v0 = *(const float4*)(xr + base);
            float4 v1 = (base + 4 < IN_F) ? *(const float4*)(xr + base + 4)
                                          : make_float4(0.f, 0.f, 0.f, 0.f);
            af[kt] = f16x8{(f16)v0.x, (f16)v0.y, (f16)v0.z, (f16)v0.w,
                           (f16)v1.x, (f16)v1.y, (f16)v1.z, (f16)v1.w};
        }
        #pragma unroll
        for (int jt = 0; jt < 4; ++jt) {
            f32x4 c4 = {};
            c4 = __builtin_amdgcn_mfma_f32_16x16x32_f16(af[0], Wl[(0 * 4 + jt) * 64 + lane], c4, 0, 0, 0);
            c4 = __builtin_amdgcn_mfma_f32_16x16x32_f16(af[1], Wl[(1 * 4 + jt) * 64 + lane], c4, 0, 0, 0);
            c4 = __builtin_amdgcn_mfma_f32_16x16x32_f16(af[2], Wl[(2 * 4 + jt) * 64 + lane], c4, 0, 0, 0);
            #pragma unroll
            for (int r = 0; r < 4; ++r)
                A[(size_t)(c * 16 + grp * 4 + r) * HID + jt * 16 + col] = c4[r] + bj[jt];
        }
    }
}

// ---------------- projm: MFMA node projections (BN fused, LOG2E-scaled pack) -
__global__ __launch_bounds__(256, 4) void k_projm(const float* __restrict__ A,
                                                  const float* __restrict__ statsPrev,
                                                  const float* __restrict__ gammaP,
                                                  const float* __restrict__ betaP,
                                                  int applyBN,
                                                  const f16* __restrict__ Wp2L,
                                                  const float* __restrict__ bsig,
                                                  const float* __restrict__ bsp,
                                                  u32* __restrict__ pA,
                                                  u32* __restrict__ pB,
                                                  float* __restrict__ statsOut) {
    __shared__ f16x8 Wl[32 * 64];   // 32 KB
    for (int i = threadIdx.x; i < 32 * 64; i += 256) Wl[i] = ((const f16x8*)Wp2L)[i];
    if (blockIdx.x == 0)
        for (int i = threadIdx.x; i < 128 * 32; i += 256) statsOut[i] = 0.f;
    __syncthreads();
    const int lane = threadIdx.x & 63;
    const int col = lane & 15;
    float sck[2][8], shk[2][8];
    #pragma unroll
    for (int kt = 0; kt < 2; ++kt)
        #pragma unroll
        for (int b = 0; b < 8; ++b) {
            int k = kt * 32 + (lane >> 4) * 8 + b;
            float scv = 1.f, shv = 0.f;
            if (applyBN) {
                float m = statsPrev[k * 32] * (1.f / N_NODES);
                float v = statsPrev[(64 + k) * 32] * (1.f / N_NODES) - m * m;
                scv = rsqrtf(v + BN_EPS) * gammaP[k];
                shv = betaP[k] - m * scv;
            }
            sck[kt][b] = scv;
            shk[kt][b] = shv;
        }
    float bAs[4], bPs[4];
    #pragma unroll
    for (int jt = 0; jt < 4; ++jt) {
        bAs[jt] = bsig[jt * 16 + col] * LOG2E;
        bPs[jt] = bsp[jt * 16 + col] * LOG2E;
    }
    const int wid = blockIdx.x * 4 + (threadIdx.x >> 6);
    const int nw = gridDim.x * 4;
    for (int c = wid; c < N_NODES / 16; c += nw) {
        const int node = c * 16 + col;
        const float4* Arow = (const float4*)(A + (size_t)node * HID);
        f16x8 af[2];
        #pragma unroll
        for (int kt = 0; kt < 2; ++kt) {
            float4 v0 = Arow[kt * 8 + (lane >> 4) * 2];
            float4 v1 = Arow[kt * 8 + (lane >> 4) * 2 + 1];
            float e0 = v0.x * sck[kt][0] + shk[kt][0];
            float e1 = v0.y * sck[kt][1] + shk[kt][1];
            float e2 = v0.z * sck[kt][2] + shk[kt][2];
            float e3 = v0.w * sck[kt][3] + shk[kt][3];
            float e4 = v1.x * sck[kt][4] + shk[kt][4];
            float e5 = v1.y * sck[kt][5] + shk[kt][5];
            float e6 = v1.z * sck[kt][6] + shk[kt][6];
            float e7 = v1.w * sck[kt][7] + shk[kt][7];
            af[kt] = f16x8{(f16)e0, (f16)e1, (f16)e2, (f16)e3,
                           (f16)e4, (f16)e5, (f16)e6, (f16)e7};
        }
        #pragma unroll
        for (int h = 0; h < 2; ++h) {
            f32x4 c4[8];
            #pragma unroll
            for (int jt2 = 0; jt2 < 8; ++jt2) {
                int jt = h * 8 + jt2;
                f32x4 acc = {};
                acc = __builtin_amdgcn_mfma_f32_16x16x32_f16(af[0], Wl[(0 * 16 + jt) * 64 + lane], acc, 0, 0, 0);
                c4[jt2] = __builtin_amdgcn_mfma_f32_16x16x32_f16(af[1], Wl[(1 * 16 + jt) * 64 + lane], acc, 0, 0, 0);
            }
            u32* dstArr = h ? pB : pA;
            #pragma unroll
            for (int jt2 = 0; jt2 < 4; ++jt2)
                #pragma unroll
                for (int r = 0; r < 4; ++r) {
                    float s = fmaf(c4[jt2][r], LOG2E, h ? 0.f : bAs[jt2]);
                    float p = fmaf(c4[jt2 + 4][r], LOG2E, h ? 0.f : bPs[jt2]);
                    int n2 = c * 16 + (lane >> 4) * 4 + r;
                    dstArr[(size_t)n2 * HID + jt2 * 16 + col] = f2bf(s) | (f2bf(p) << 16);
                }
        }
    }
}

// ---------------- nodeagg: dual-context interleaved MFMA gather-reduce -------
// Two independent edge-ranges per wave (adjacent for L2 locality). Loads for
// both contexts issue before either computes -> 2x memory streams per wave.
// Scalar (SGPR) control flow via readfirstlane; B-fragments in LDS.

#define CTX_DECL_INIT(S, widx)                                                \
    int n##S = __builtin_amdgcn_readfirstlane(partW[widx]);                   \
    const int ne##S = __builtin_amdgcn_readfirstlane(partW[(widx) + 1]);      \
    bool act##S = n##S < ne##S;                                               \
    int rb##S = 0, re##S = 0;                                                 \
    float resid##S = 0.f;                                                     \
    float bsg##S[4], bsp##S[4], accv##S[4];                                   \
    int s0##S = 0, s1##S = 0, s2##S = 0, s3##S = 0;                           \
    {                                                                         \
        _Pragma("unroll")                                                     \
        for (int jt = 0; jt < 4; ++jt) {                                      \
            bsg##S[jt] = 0.f; bsp##S[jt] = 0.f; accv##S[jt] = 0.f;            \
        }                                                                     \
        if (act##S) {                                                         \
            rb##S = __builtin_amdgcn_readfirstlane(rowptr[n##S]);             \
            re##S = __builtin_amdgcn_readfirstlane(rowptr[n##S + 1]);         \
            resid##S = A[(size_t)n##S * HID + lane];                          \
            if (applyBN) resid##S = resid##S * scL + shL;                     \
            _Pragma("unroll")                                                 \
            for (int jt = 0; jt < 4; ++jt) {                                  \
                u32 pb = pBv[(size_t)n##S * HID + jt * 16 + col];             \
                bsg##S[jt] = __uint_as_float(pb << 16);                       \
                bsp##S[jt] = __uint_as_float(pb & 0xffff0000u);               \
            }                                                                 \
            const int* sp = srcS + rb##S + rowb;                              \
            s0##S = sp[0]; s1##S = sp[1]; s2##S = sp[2]; s3##S = sp[3];       \
        }                                                                     \
    }

#define STEP_LOADS(S)                                                         \
    u32 ga##S[4][4];                                                          \
    f16x8 a0##S, a1##S;                                                       \
    if (act##S) {                                                             \
        const u32* g0##S = pAv + (size_t)s0##S * HID + col;                   \
        const u32* g1##S = pAv + (size_t)s1##S * HID + col;                   \
        const u32* g2##S = pAv + (size_t)s2##S * HID + col;                   \
        const u32* g3##S = pAv + (size_t)s3##S * HID + col;                   \
        _Pragma("unroll")                                                     \
        for (int jt = 0; jt < 4; ++jt) {                                      \
            ga##S[jt][0] = g0##S[jt * 16];                                    \
            ga##S[jt][1] = g1##S[jt * 16];                                    \
            ga##S[jt][2] = g2##S[jt * 16];                                    \
            ga##S[jt][3] = g3##S[jt * 16];                                    \
        }                                                                     \
        const f16x8* arow##S = (const f16x8*)(eapS + (size_t)(rb##S + col) * ROW_U32); \
        a0##S = arow##S[grp];                                                 \
        a1##S = arow##S[4 + grp];                                             \
    }

#define STEP_COMPUTE(S)                                                       \
    if (act##S) {                                                             \
        const int cnt##S = re##S - rb##S;                                     \
        if (cnt##S > 0) {                                                     \
            _Pragma("unroll")                                                 \
            for (int jt = 0; jt < 4; ++jt) {                                  \
                f32x4 cs = {bsg##S[jt], bsg##S[jt], bsg##S[jt], bsg##S[jt]};  \
                f32x4 cp = {bsp##S[jt], bsp##S[jt], bsp##S[jt], bsp##S[jt]};  \
                f16x8 w0s = Wlds[(jt) * 64 + lane];                           \
                f16x8 w1s = Wlds[(8 + jt) * 64 + lane];                       \
                f16x8 w0p = Wlds[(4 + jt) * 64 + lane];                       \
                f16x8 w1p = Wlds[(12 + jt) * 64 + lane];                      \
                cs = __builtin_amdgcn_mfma_f32_16x16x32_f16(a0##S, w0s, cs, 0, 0, 0); \
                cs = __builtin_amdgcn_mfma_f32_16x16x32_f16(a1##S, w1s, cs, 0, 0, 0); \
                cp = __builtin_amdgcn_mfma_f32_16x16x32_f16(a0##S, w0p, cp, 0, 0, 0); \
                cp = __builtin_amdgcn_mfma_f32_16x16x32_f16(a1##S, w1p, cp, 0, 0, 0); \
                _Pragma("unroll")                                             \
                for (int r = 0; r < 4; ++r) {                                 \
                    float s_ = cs[r] + __uint_as_float(ga##S[jt][r] << 16);   \
                    float p_ = cp[r] + __uint_as_float(ga##S[jt][r] & 0xffff0000u); \
                    float g_ = __builtin_amdgcn_rcpf(1.f + exp2f(-s_));       \
                    float m_ = fmaxf(p_, 0.f) + log2f(1.f + exp2f(-fabsf(p_))); \
                    accv##S[jt] += (rowb + r < cnt##S) ? g_ * m_ : 0.f;       \
                }                                                             \
            }                                                                 \
            rb##S += 16;                                                      \
        }                                                                     \
        while (rb##S >= re##S) {                                              \
            _Pragma("unroll")                                                 \
            for (int jt = 0; jt < 4; ++jt) {                                  \
                accv##S[jt] += __shfl_xor(accv##S[jt], 16);                   \
                accv##S[jt] += __shfl_xor(accv##S[jt], 32);                   \
            }                                                                 \
            float accSel = (lane & 32) ? ((lane & 16) ? accv##S[3] : accv##S[2]) \
                                       : ((lane & 16) ? accv##S[1] : accv##S[0]); \
            float outv = resid##S + accSel * LN2;                             \
            Aout[(size_t)n##S * HID + lane] = outv;                           \
            lsum += outv;                                                     \
            lsq += outv * outv;                                               \
            accv##S[0] = accv##S[1] = accv##S[2] = accv##S[3] = 0.f;          \
            rb##S = re##S;                                                    \
            ++n##S;                                                           \
            if (n##S >= ne##S) { act##S = false; break; }                     \
            re##S = __builtin_amdgcn_readfirstlane(rowptr[n##S + 1]);         \
            resid##S = A[(size_t)n##S * HID + lane];                          \
            if (applyBN) resid##S = resid##S * scL + shL;                     \
            _Pragma("unroll")                                                 \
            for (int jt = 0; jt < 4; ++jt) {                                  \
                u32 pb = pBv[(size_t)n##S * HID + jt * 16 + col];             \
                bsg##S[jt] = __uint_as_float(pb << 16);                       \
                bsp##S[jt] = __uint_as_float(pb & 0xffff0000u);               \
            }                                                                 \
        }                                                                     \
        if (act##S) {                                                         \
            const int* sp##S = srcS + rb##S + rowb;                           \
            s0##S = sp##S[0]; s1##S = sp##S[1];                               \
            s2##S = sp##S[2]; s3##S = sp##S[3];                               \
        }                                                                     \
    }

__global__ __launch_bounds__(256, 4) void k_nodeagg(const float* __restrict__ A,
                                                    const float* __restrict__ statsPrev,
                                                    const float* __restrict__ gammaP,
                                                    const float* __restrict__ betaP,
                                                    int applyBN,
                                                    const u32* __restrict__ pAv,
                                                    const u32* __restrict__ pBv,
                                                    const u32* __restrict__ eapS,
                                                    const int* __restrict__ srcS,
                                                    const int* __restrict__ rowptr,
                                                    const int* __restrict__ partW,
                                                    const f16* __restrict__ Wf16L,
                                                    float* __restrict__ Aout,
                                                    float* __restrict__ statsOut) {
    __shared__ f16x8 Wlds[16 * 64];   // 16 KB B-fragments
    __shared__ float redS[256], redQ[256];
    for (int i = threadIdx.x; i < 16 * 64; i += 256)
        Wlds[i] = ((const f16x8*)Wf16L)[i];

    const int lane = threadIdx.x & 63;
    const int col = lane & 15;
    const int grp = lane >> 4;
    const int rowb = grp * 4;

    float scL = 1.f, shL = 0.f;
    if (applyBN) {
        float m = statsPrev[lane * 32] * (1.f / N_NODES);
        float v = statsPrev[(64 + lane) * 32] * (1.f / N_NODES) - m * m;
        scL = rsqrtf(v + BN_EPS) * gammaP[lane];
        shL = betaP[lane] - m * scL;
    }
    __syncthreads();

    const int w2 = (((blockIdx.x << 2) + (threadIdx.x >> 6)) << 1);
    float lsum = 0.f, lsq = 0.f;

    CTX_DECL_INIT(A, w2)
    CTX_DECL_INIT(B, w2 + 1)

    while (actA || actB) {
        STEP_LOADS(A)
        STEP_LOADS(B)
        STEP_COMPUTE(A)
        STEP_COMPUTE(B)
    }

    redS[threadIdx.x] = lsum;
    redQ[threadIdx.x] = lsq;
    __syncthreads();
    if (threadIdx.x < 64) {
        float s = redS[threadIdx.x] + redS[threadIdx.x + 64] + redS[threadIdx.x + 128] + redS[threadIdx.x + 192];
        float q = redQ[threadIdx.x] + redQ[threadIdx.x + 64] + redQ[threadIdx.x + 128] + redQ[threadIdx.x + 192];
        unsafeAtomicAdd(&statsOut[threadIdx.x * 32], s);
        unsafeAtomicAdd(&statsOut[(64 + threadIdx.x) * 32], q);
    }
}

// ---------------- pool (+ final BN): segment-sum over sorted graph_idx ------
__global__ __launch_bounds__(256) void k_poolbn(const float* __restrict__ A,
                                                const float* __restrict__ stats,
                                                const float* __restrict__ gamma,
                                                const float* __restrict__ beta,
                                                const int* __restrict__ gidx,
                                                float* __restrict__ gf) {
    const int lane = threadIdx.x & 63;
    float m = stats[lane * 32] * (1.f / N_NODES);
    float v = stats[(64 + lane) * 32] * (1.f / N_NODES) - m * m;
    float scv = rsqrtf(v + BN_EPS) * gamma[lane];
    float shv = beta[lane] - m * scv;
    const int wid = blockIdx.x * 4 + (threadIdx.x >> 6);
    const int nwaves = gridDim.x * 4;
    const int chunk = (N_NODES + nwaves - 1) / nwaves;
    int r0 = wid * chunk;
    if (r0 >= N_NODES) return;
    int r1 = min(r0 + chunk, N_NODES);
    int gcur = gidx[r0];
    float acc = 0.f;
    for (int r = r0; r < r1; ++r) {
        int g = gidx[r];
        if (g != gcur) {
            unsafeAtomicAdd(&gf[(size_t)gcur * HID + lane], acc);
            acc = 0.f;
            gcur = g;
        }
        acc += A[(size_t)r * HID + lane] * scv + shv;
    }
    unsafeAtomicAdd(&gf[(size_t)gcur * HID + lane], acc);
}

// ---------------- readout ----------------
__global__ __launch_bounds__(256) void k_readout(const float* __restrict__ gf,
                                                 const float* __restrict__ Wfc,
                                                 const float* __restrict__ bfc,
                                                 const float* __restrict__ Wout,
                                                 const float* __restrict__ bout,
                                                 float* __restrict__ out) {
    const int lane = threadIdx.x & 63;
    const int g = blockIdx.x * 4 + (threadIdx.x >> 6);
    if (g >= N_GRAPHS) return;
    const float* row = gf + (size_t)g * HID;
    float p0 = bfc[lane], p1 = bfc[64 + lane];
    #pragma unroll 4
    for (int k = 0; k < HID; ++k) {
        float v = row[k];
        p0 += v * Wfc[k * PRED + lane];
        p1 += v * Wfc[k * PRED + 64 + lane];
    }
    float part = p0 * Wout[lane] + p1 * Wout[64 + lane];
    #pragma unroll
    for (int off = 32; off > 0; off >>= 1) part += __shfl_xor(part, off);
    if (lane == 0) out[g] = part + bout[0];
}

extern "C" void kernel_launch(void* const* d_in, const int* in_sizes, int n_in,
                              void* d_out, int out_size, void* d_ws, size_t ws_size,
                              hipStream_t stream) {
    const float* x         = (const float*)d_in[0];
    const float* edge_attr = (const float*)d_in[1];
    const int*   src       = (const int*)d_in[2];
    const int*   dst       = (const int*)d_in[3];
    const int*   gidx      = (const int*)d_in[4];
    const float* W_embed   = (const float*)d_in[6];
    const float* b_embed   = (const float*)d_in[7];
    const float* W_sig     = (const float*)d_in[8];
    const float* b_sig     = (const float*)d_in[9];
    const float* W_sp      = (const float*)d_in[10];
    const float* b_sp      = (const float*)d_in[11];
    const float* bn_gamma  = (const float*)d_in[12];
    const float* bn_beta   = (const float*)d_in[13];
    const float* W_fc      = (const float*)d_in[14];
    const float* b_fc      = (const float*)d_in[15];
    const float* W_out     = (const float*)d_in[16];
    const float* b_out     = (const float*)d_in[17];
    float* out = (float*)d_out;

    const size_t NH = (size_t)N_NODES * HID;
    float* ws     = (float*)d_ws;
    float* A      = ws;                                   // NH f32
    u32*   pA     = (u32*)(A + NH);                       // NH u32 (bf16x2, LOG2E-scaled)
    u32*   pB     = pA + NH;                              // NH u32
    u32*   eapS   = pB + NH;                              // (E+32)*24 u32
    int*   srcS   = (int*)(eapS + (size_t)(N_EDGES + 32) * ROW_U32);  // E+32 (padded)
    int*   iperm  = srcS + N_EDGES + 32;                  // E
    int*   rowptr = iperm + N_EDGES;                      // N+1
    int*   deg    = rowptr + N_NODES + 1;                 // N
    int*   cursor = deg + N_NODES;                        // N
    int*   partial    = cursor + N_NODES;                 // 256
    int*   partialExc = partial + 256;                    // 256
    int*   partW  = partialExc + 256;                     // NW2+1
    f16*   Wf16   = (f16*)(partW + NW2 + 2);              // 3*2*8*64*8 f16
    f16*   Wp2    = Wf16 + 3 * 2 * 8 * 64 * 8;            // 3*2*16*64*8 f16
    f16*   Wef    = Wp2 + 3 * 2 * 16 * 64 * 8;            // 3*4*64*8 f16
    float* stats  = (float*)(Wef + 3 * 4 * 64 * 8);       // 3 * 4096 f32
    float* gf     = stats + 3 * 4096;                     // G*HID

    // ---- prep: weights, zeros, CSR, partition (once per call) ----
    k_wprepAll<<<39, 256, 0, stream>>>(W_sig, W_sp, W_embed, Wf16, Wp2, Wef);
    k_zeroAll<<<(2 * N_NODES + N_GRAPHS * HID + 255) / 256, 256, 0, stream>>>(
        deg, 2 * N_NODES, gf, N_GRAPHS * HID);
    k_hist<<<(N_EDGES + 255) / 256, 256, 0, stream>>>(dst, deg);
    k_scanA<<<SCAN_BLOCKS, 256, 0, stream>>>(deg, partial);
    k_scanB<<<1, 256, 0, stream>>>(partial, partialExc, rowptr);
    k_scanC<<<SCAN_BLOCKS, 256, 0, stream>>>(deg, partialExc, rowptr);
    k_part<<<(NW2 + 1 + 255) / 256, 256, 0, stream>>>(rowptr, partW);
    k_rank<<<(N_EDGES + 32 + 255) / 256, 256, 0, stream>>>(dst, src, rowptr, cursor, srcS, iperm);
    k_embedm<<<512, 256, 0, stream>>>(x, Wef, b_embed, A);
    k_epackS<<<4096, 256, 0, stream>>>(edge_attr, iperm, eapS);

    for (int i = 0; i < 3; ++i) {
        const float* stPrev = stats + (size_t)(i > 0 ? i - 1 : 0) * 4096;
        const float* gP     = bn_gamma + (i > 0 ? i - 1 : 0) * HID;
        const float* bP     = bn_beta + (i > 0 ? i - 1 : 0) * HID;
        float* stOut        = stats + (size_t)i * 4096;
        int applyBN = (i > 0) ? 1 : 0;
        k_projm<<<512, 256, 0, stream>>>(A, stPrev, gP, bP, applyBN,
                                         Wp2 + (size_t)i * 2 * 16 * 64 * 8,
                                         b_sig + i * HID, b_sp + i * HID,
                                         pA, pB, stOut);
        k_nodeagg<<<NAGG_BLOCKS, 256, 0, stream>>>(A, stPrev, gP, bP, applyBN,
                                                   pA, pB, eapS, srcS, rowptr, partW,
                                                   Wf16 + (size_t)i * 2 * 8 * 64 * 8,
                                                   A, stOut);
    }

    k_poolbn<<<256, 256, 0, stream>>>(A, stats + 2 * 4096, bn_gamma + 2 * HID,
                                      bn_beta + 2 * HID, gidx, gf);
    k_readout<<<(N_GRAPHS + 3) / 4, 256, 0, stream>>>(gf, W_fc, b_fc, W_out, b_out, out);
}